// Round 22
// baseline (541.933 us; speedup 1.0000x reference)
//
#include <hip/hip_runtime.h>
#include <math.h>

#define N_NODES 50000
#define N_EDGES 800000
#define HID 64
#define HEADS 4
#define HC 256
#define NEG_SLOPE 0.2f
#define LN_EPS 1e-5f
#define EDGE_BLOCKS 2048   // persistent-wave grid for k_edgeagg (8192 waves)
#define NTM_BLOCKS 783     // 782 node blocks + edge-slice coverage (783*1022 >= 800000)

typedef __attribute__((ext_vector_type(8))) short bf16x8;
typedef __attribute__((ext_vector_type(8))) unsigned short u16x8;
typedef __attribute__((ext_vector_type(4))) float f32x4;

__device__ __forceinline__ float bf2f(unsigned short u) {
    return __uint_as_float(((unsigned int)u) << 16);
}
__device__ __forceinline__ unsigned short f2bf(float f) {
    unsigned int u = __float_as_uint(f);
    u = (u + 0x7fffu + ((u >> 16) & 1u)) >> 16;   // RNE
    return (unsigned short)u;
}
__device__ __forceinline__ float fast_tanh(float v) {
    const float c = fminf(fmaxf(v, -15.f), 15.f);
    const float e = __expf(2.f * c);
    return 1.f - 2.f / (e + 1.f);
}
__device__ __forceinline__ bf16x8 pack_bf8(float4 a, float4 b) {
    u16x8 r;
    r[0] = f2bf(a.x); r[1] = f2bf(a.y); r[2] = f2bf(a.z); r[3] = f2bf(a.w);
    r[4] = f2bf(b.x); r[5] = f2bf(b.y); r[6] = f2bf(b.z); r[7] = f2bf(b.w);
    return __builtin_bit_cast(bf16x8, r);
}

// ---------------- K1: MFMA node transform + fused hist + ea->bf16 + permw --
__global__ __launch_bounds__(256) void k_ntm(
    const float* __restrict__ x,
    const float* __restrict__ W_l, const float* __restrict__ b_l,
    const float* __restrict__ W_r, const float* __restrict__ b_r,
    const int* __restrict__ ei, int* __restrict__ count,
    const float* __restrict__ edge_attr, unsigned short* __restrict__ ea_bf,
    const int do_ea,
    const float* __restrict__ W1, const float* __restrict__ b1,
    const float* __restrict__ gamma, const float* __restrict__ beta,
    const float* __restrict__ bias_gat, const float* __restrict__ W2,
    float* __restrict__ W1p, float* __restrict__ b1p,
    float* __restrict__ gammap, float* __restrict__ betap,
    float* __restrict__ biasgp, float* __restrict__ W2p,
    unsigned short* __restrict__ xl_t, unsigned short* __restrict__ xr_t)
{
    __shared__ unsigned short wl_s[2][16][64][8];   // 32 KB
    __shared__ unsigned short wr_s[2][16][64][8];   // 32 KB
    const int t = threadIdx.x, lane = t & 63, wv = t >> 6;
    const int arow = lane & 15, koct = lane >> 4;
    const int bid = blockIdx.x;

    // ---- hist slice (independent of node work) ----
    {
        const int e0 = bid * 1022;
#pragma unroll
        for (int j = 0; j < 4; j++) {
            const int e = e0 + j * 256 + t;
            if (e < e0 + 1022 && e < N_EDGES) atomicAdd(&count[ei[N_EDGES + e]], 1);
        }
    }
    // ---- edge_attr -> bf16 slice (coalesced, original edge order) ----
    if (do_ea) {
        const long long i0 = (long long)bid * 1022 * 8;             // float4-chunk index base
        const long long iend = i0 + 1022 * 8;
        const long long itot = (long long)N_EDGES * 8;
        for (int j = 0; j < 32; j++) {
            const long long idx = i0 + (long long)j * 256 + t;
            if (idx < iend && idx < itot) {
                const float4 v = *(const float4*)(edge_attr + idx * 4);
                *(ushort4*)(ea_bf + idx * 4) =
                    make_ushort4(f2bf(v.x), f2bf(v.y), f2bf(v.z), f2bf(v.w));
            }
        }
    }
    // ---- permw slice (last block only) ----
    if (bid == NTM_BLOCKS - 1) {
        const int c = t;
        const int pos = (c & 15) * 16 + (c >> 4);
        for (int k = 0; k < 64; k++) W1p[k * 256 + pos] = W1[k * 256 + c];
        b1p[pos] = b1[c];
        gammap[pos] = gamma[c];
        betap[pos] = beta[c];
        biasgp[pos] = bias_gat[c];
        for (int j = 0; j < 64; j++) W2p[pos * 64 + j] = W2[c * 64 + j];
    }

    // ---- W staging ----
    for (int i = t; i < 2048; i += 256) {
        const int ks = i >> 10, nt = (i >> 6) & 15, ls = i & 63;
        const int col = nt * 16 + (ls & 15);
        const int kb = ks * 32 + (ls >> 4) * 8;
        unsigned short a[8], b[8];
#pragma unroll
        for (int j = 0; j < 8; j++) {
            a[j] = f2bf(W_l[(kb + j) * 256 + col]);
            b[j] = f2bf(W_r[(kb + j) * 256 + col]);
        }
        *(ushort4*)&wl_s[ks][nt][ls][0] = make_ushort4(a[0], a[1], a[2], a[3]);
        *(ushort4*)&wl_s[ks][nt][ls][4] = make_ushort4(a[4], a[5], a[6], a[7]);
        *(ushort4*)&wr_s[ks][nt][ls][0] = make_ushort4(b[0], b[1], b[2], b[3]);
        *(ushort4*)&wr_s[ks][nt][ls][4] = make_ushort4(b[4], b[5], b[6], b[7]);
    }
    __syncthreads();

    const int n0w = bid * 64 + wv * 16;
    if (n0w >= N_NODES) return;

    const float* xrow = x + (size_t)(n0w + arow) * 64;
    const bf16x8 af0 = pack_bf8(*(const float4*)(xrow + koct * 8),
                                *(const float4*)(xrow + koct * 8 + 4));
    const bf16x8 af1 = pack_bf8(*(const float4*)(xrow + 32 + koct * 8),
                                *(const float4*)(xrow + 32 + koct * 8 + 4));

    float acc[4][16];
#pragma unroll
    for (int nt = 0; nt < 16; nt++) {
        const float bv = b_l[nt * 16 + arow];
        f32x4 d = {bv, bv, bv, bv};
        d = __builtin_amdgcn_mfma_f32_16x16x32_bf16(af0, *(const bf16x8*)&wl_s[0][nt][lane][0], d, 0, 0, 0);
        d = __builtin_amdgcn_mfma_f32_16x16x32_bf16(af1, *(const bf16x8*)&wl_s[1][nt][lane][0], d, 0, 0, 0);
#pragma unroll
        for (int r = 0; r < 4; r++) acc[r][nt] = d[r];
    }
#pragma unroll
    for (int r = 0; r < 4; r++) {
        u16x8 lo, hi;
#pragma unroll
        for (int j = 0; j < 8; j++) { lo[j] = f2bf(acc[r][j]); hi[j] = f2bf(acc[r][j + 8]); }
        unsigned short* dst = xl_t + (size_t)(n0w + koct * 4 + r) * 256 + arow * 16;
        *(u16x8*)dst = lo;
        *(u16x8*)(dst + 8) = hi;
    }
#pragma unroll
    for (int nt = 0; nt < 16; nt++) {
        const float bv = b_r[nt * 16 + arow];
        f32x4 d = {bv, bv, bv, bv};
        d = __builtin_amdgcn_mfma_f32_16x16x32_bf16(af0, *(const bf16x8*)&wr_s[0][nt][lane][0], d, 0, 0, 0);
        d = __builtin_amdgcn_mfma_f32_16x16x32_bf16(af1, *(const bf16x8*)&wr_s[1][nt][lane][0], d, 0, 0, 0);
#pragma unroll
        for (int r = 0; r < 4; r++) acc[r][nt] = d[r];
    }
#pragma unroll
    for (int r = 0; r < 4; r++) {
        u16x8 lo, hi;
#pragma unroll
        for (int j = 0; j < 8; j++) { lo[j] = f2bf(acc[r][j]); hi[j] = f2bf(acc[r][j + 8]); }
        unsigned short* dst = xr_t + (size_t)(n0w + koct * 4 + r) * 256 + arow * 16;
        *(u16x8*)dst = lo;
        *(u16x8*)(dst + 8) = hi;
    }
}

// ---------------- K3: exclusive scan (single block) ------------------------
__global__ __launch_bounds__(1024) void k_scan(const int* __restrict__ count, int* __restrict__ off)
{
    __shared__ int wsum[16];
    __shared__ int s_carry;
    const int t = threadIdx.x, lane = t & 63, wv = t >> 6;
    if (t == 0) s_carry = 0;
    __syncthreads();
    for (int base = 0; base < N_NODES; base += 8192) {
        const int idx0 = base + t * 8;
        int v[8];
#pragma unroll
        for (int j = 0; j < 8; j++) { int i = idx0 + j; v[j] = (i < N_NODES) ? count[i] : 0; }
#pragma unroll
        for (int j = 1; j < 8; j++) v[j] += v[j - 1];
        const int tot = v[7];
        int sc = tot;
#pragma unroll
        for (int s = 1; s < 64; s <<= 1) { int o = __shfl_up(sc, s, 64); if (lane >= s) sc += o; }
        if (lane == 63) wsum[wv] = sc;
        __syncthreads();
        const int carry = s_carry;
        int woff = 0;
        for (int u = 0; u < wv; u++) woff += wsum[u];
        const int ebase = carry + woff + (sc - tot);
#pragma unroll
        for (int j = 0; j < 8; j++) {
            int i = idx0 + j;
            if (i < N_NODES) off[i] = ebase + (j ? v[j - 1] : 0);
        }
        __syncthreads();
        if (t == 0) { int tt = 0; for (int u = 0; u < 16; u++) tt += wsum[u]; s_carry = carry + tt; }
        __syncthreads();
    }
    if (threadIdx.x == 0) off[N_NODES] = s_carry;
}

// ---------------- K4: scatter src + eid into CSR (index-only, 4B) ----------
__global__ __launch_bounds__(256) void k_scatter(
    const int* __restrict__ ei, const int* __restrict__ off, int* __restrict__ cursor,
    int* __restrict__ csr_src, int* __restrict__ eid_csr)
{
    const int e = blockIdx.x * 256 + threadIdx.x;
    if (e < N_EDGES) {
        const int s = ei[e];
        const int d = ei[N_EDGES + e];
        const int pos = off[d] + atomicAdd(&cursor[d], 1);
        csr_src[pos] = s;
        eid_csr[pos] = e;
    }
}

// ---------------- K5: edge+aggregate, persistent waves, deep pipeline ------
// EABF: A-frags loaded directly from pre-converted bf16 ea_bf (16B/lane).
template<bool F32, bool EABF>
__global__ __launch_bounds__(256) void k_edgeagg(
    const int* __restrict__ off, const int* __restrict__ csr_src,
    const int* __restrict__ eid_csr, const float* __restrict__ edge_attr,
    const unsigned short* __restrict__ ea_bf,
    const float* __restrict__ W_e, const float* __restrict__ att,
    const unsigned short* __restrict__ xl_t, const unsigned short* __restrict__ xr_t,
    void* __restrict__ zs_g)
{
    __shared__ unsigned short bfrag_s[16][64][8];   // 16 KB, only LDS

    const int t = threadIdx.x;
    const int lane = t & 63, wv = t >> 6;
    const int arow = lane & 15, koct = lane >> 4;

    for (int i = t; i < 1024; i += 256) {
        const int nt = i >> 6, ls = i & 63;
        const int col = nt * 16 + (ls & 15);
        const int kb = (ls >> 4) * 8;
        unsigned short tmp[8];
#pragma unroll
        for (int j = 0; j < 8; j++) tmp[j] = f2bf(W_e[(kb + j) * 256 + col]);
        *(ushort4*)&bfrag_s[nt][ls][0] = make_ushort4(tmp[0], tmp[1], tmp[2], tmp[3]);
        *(ushort4*)&bfrag_s[nt][ls][4] = make_ushort4(tmp[4], tmp[5], tmp[6], tmp[7]);
    }
    __syncthreads();

    float attLf[8], attHf[8];
#pragma unroll
    for (int j = 0; j < 8; j++) {
        attLf[j] = att[j * 16 + arow];
        attHf[j] = att[(j + 8) * 16 + arow];
    }

    const int STRIDE = EDGE_BLOCKS * 4;
    int node = blockIdx.x * 4 + wv;
    if (node >= N_NODES) return;

    int lo = off[node], hi = off[node + 1];
    u16x8 xrl = *(const u16x8*)(xr_t + (size_t)node * 256 + arow * 16);
    u16x8 xrh = *(const u16x8*)(xr_t + (size_t)node * 256 + arow * 16 + 8);
    while (hi <= lo) {
        if (F32) *(float4*)((float*)zs_g + (size_t)node * 256 + arow * 16 + koct * 4) = make_float4(0.f, 0.f, 0.f, 0.f);
        else *(ushort4*)((unsigned short*)zs_g + (size_t)node * 256 + arow * 16 + koct * 4) = make_ushort4(0, 0, 0, 0);
        node += STRIDE;
        if (node >= N_NODES) return;
        lo = off[node]; hi = off[node + 1];
        xrl = *(const u16x8*)(xr_t + (size_t)node * 256 + arow * 16);
        xrh = *(const u16x8*)(xr_t + (size_t)node * 256 + arow * 16 + 8);
    }
    int svbase = lo;
    int svall = csr_src[min(svbase + lane, hi - 1)];
    int evall = eid_csr[min(svbase + lane, hi - 1)];

    int nnode = node + STRIDE;
    bool nvalid = nnode < N_NODES;
    int nlo = 0, nhi = 0, nsvall = 0, nevall = 0;
    u16x8 nxrl = xrl, nxrh = xrh;
    if (nvalid) {
        nlo = off[nnode]; nhi = off[nnode + 1];
        nxrl = *(const u16x8*)(xr_t + (size_t)nnode * 256 + arow * 16);
        nxrh = *(const u16x8*)(xr_t + (size_t)nnode * 256 + arow * 16 + 8);
        if (nhi > nlo) {
            nsvall = csr_src[min(nlo + lane, nhi - 1)];
            nevall = eid_csr[min(nlo + lane, nhi - 1)];
        }
    }
    int p0 = lo;
    bf16x8 af;
    u16x8 xlo[4], xhi[4];
    {
        const int eid0 = __shfl(evall, arow, 64);
        if (EABF) {
            af = *(const bf16x8*)(ea_bf + (size_t)eid0 * 32 + koct * 8);
        } else {
            const float* ap = edge_attr + (size_t)eid0 * 32 + koct * 8;
            af = pack_bf8(*(const float4*)ap, *(const float4*)(ap + 4));
        }
#pragma unroll
        for (int r = 0; r < 4; r++) {
            const int sr = __shfl(svall, koct * 4 + r, 64);
            const unsigned short* bp = xl_t + (size_t)sr * 256 + arow * 16;
            xlo[r] = *(const u16x8*)bp;
            xhi[r] = *(const u16x8*)(bp + 8);
        }
    }

    float g[16];
#pragma unroll
    for (int i = 0; i < 16; i++) g[i] = 0.f;
    float dsum[4] = {0.f, 0.f, 0.f, 0.f};

    for (;;) {
        const bool last = (p0 + 16 >= hi);
        bool uvalid;
        int up0;
        if (!last) { uvalid = true; up0 = p0 + 16; }
        else {
            while (nvalid && nlo >= nhi) {
                if (F32) *(float4*)((float*)zs_g + (size_t)nnode * 256 + arow * 16 + koct * 4) = make_float4(0.f, 0.f, 0.f, 0.f);
                else *(ushort4*)((unsigned short*)zs_g + (size_t)nnode * 256 + arow * 16 + koct * 4) = make_ushort4(0, 0, 0, 0);
                nnode += STRIDE;
                nvalid = nnode < N_NODES;
                if (nvalid) {
                    nlo = off[nnode]; nhi = off[nnode + 1];
                    nxrl = *(const u16x8*)(xr_t + (size_t)nnode * 256 + arow * 16);
                    nxrh = *(const u16x8*)(xr_t + (size_t)nnode * 256 + arow * 16 + 8);
                    if (nhi > nlo) {
                        nsvall = csr_src[min(nlo + lane, nhi - 1)];
                        nevall = eid_csr[min(nlo + lane, nhi - 1)];
                    }
                }
            }
            uvalid = nvalid; up0 = nlo;
        }
        u16x8 uAb = {0, 0, 0, 0, 0, 0, 0, 0};
        float4 uA0 = make_float4(0.f, 0.f, 0.f, 0.f), uA1 = uA0;
        if (uvalid) {
            const int ubase = last ? 0 : (up0 - svbase);
            const int uev = last ? nevall : evall;
            const int ueid = __shfl(uev, ubase + arow, 64);
            if (EABF) {
                uAb = *(const u16x8*)(ea_bf + (size_t)ueid * 32 + koct * 8);
            } else {
                const float* ap = edge_attr + (size_t)ueid * 32 + koct * 8;
                uA0 = *(const float4*)ap;
                uA1 = *(const float4*)(ap + 4);
            }
        }

        float s_[4][4];
#pragma unroll
        for (int r = 0; r < 4; r++)
#pragma unroll
            for (int h = 0; h < 4; h++) s_[r][h] = 0.f;

#pragma unroll
        for (int nt = 0; nt < 8; nt++) {
            const bf16x8 bfr = *(const bf16x8*)&bfrag_s[nt][lane][0];
            const float xrv = bf2f((unsigned short)xrl[nt]);
            f32x4 dacc = {xrv, xrv, xrv, xrv};
            dacc = __builtin_amdgcn_mfma_f32_16x16x32_bf16(af, bfr, dacc, 0, 0, 0);
            const float atv = attLf[nt];
            const int h = nt >> 2;
#pragma unroll
            for (int r = 0; r < 4; r++) {
                const float mm = dacc[r] + bf2f((unsigned short)xlo[r][nt]);
                const float lk = fmaxf(mm, NEG_SLOPE * mm);
                s_[r][h] = fmaf(atv, lk, s_[r][h]);
            }
        }
        u16x8 uxlo[4], uxhi[4];
        if (uvalid) {
            const int ubase = last ? 0 : (up0 - svbase);
            const int usrcv = last ? nsvall : svall;
#pragma unroll
            for (int r = 0; r < 4; r++) {
                const int sr = __shfl(usrcv, ubase + koct * 4 + r, 64);
                const unsigned short* bp = xl_t + (size_t)sr * 256 + arow * 16;
                uxlo[r] = *(const u16x8*)bp;
                uxhi[r] = *(const u16x8*)(bp + 8);
            }
        } else {
#pragma unroll
            for (int r = 0; r < 4; r++) { uxlo[r] = xlo[r]; uxhi[r] = xhi[r]; }
        }
#pragma unroll
        for (int n2 = 0; n2 < 8; n2++) {
            const int nt = n2 + 8;
            const bf16x8 bfr = *(const bf16x8*)&bfrag_s[nt][lane][0];
            const float xrv = bf2f((unsigned short)xrh[n2]);
            f32x4 dacc = {xrv, xrv, xrv, xrv};
            dacc = __builtin_amdgcn_mfma_f32_16x16x32_bf16(af, bfr, dacc, 0, 0, 0);
            const float atv = attHf[n2];
            const int h = nt >> 2;
#pragma unroll
            for (int r = 0; r < 4; r++) {
                const float mm = dacc[r] + bf2f((unsigned short)xhi[r][n2]);
                const float lk = fmaxf(mm, NEG_SLOPE * mm);
                s_[r][h] = fmaf(atv, lk, s_[r][h]);
            }
        }
#pragma unroll
        for (int r = 0; r < 4; r++)
#pragma unroll
            for (int h = 0; h < 4; h++) {
                float v = s_[r][h];
                v += __shfl_xor(v, 1, 64);
                v += __shfl_xor(v, 2, 64);
                v += __shfl_xor(v, 4, 64);
                v += __shfl_xor(v, 8, 64);
                s_[r][h] = v;
            }
#pragma unroll
        for (int h = 0; h < 4; h++) {
            float w4[4];
#pragma unroll
            for (int r = 0; r < 4; r++) {
                const bool ok = (p0 + koct * 4 + r) < hi;
                w4[r] = ok ? __expf(fminf(s_[r][h], 60.f)) : 0.f;
            }
            dsum[h] += (w4[0] + w4[1]) + (w4[2] + w4[3]);
#pragma unroll
            for (int q = 0; q < 4; q++) {
                const int nt = h * 4 + q;
                float acc = g[nt];
#pragma unroll
                for (int r = 0; r < 4; r++) {
                    const float xv = bf2f((unsigned short)(nt < 8 ? xlo[r][nt & 7] : xhi[r][nt & 7]));
                    acc = fmaf(w4[r], xv, acc);
                }
                g[nt] = acc;
            }
        }

        if (last) {
#pragma unroll
            for (int i = 0; i < 16; i++) {
                float v = g[i];
                v += __shfl_xor(v, 16, 64);
                v += __shfl_xor(v, 32, 64);
                g[i] = v;
            }
#pragma unroll
            for (int h = 0; h < 4; h++) {
                float v = dsum[h];
                v += __shfl_xor(v, 16, 64);
                v += __shfl_xor(v, 32, 64);
                dsum[h] = v;
            }
            const float inv = 1.f / (dsum[koct] + 1e-16f);
            if (F32) {
                *(float4*)((float*)zs_g + (size_t)node * 256 + arow * 16 + koct * 4) =
                    make_float4(g[koct * 4] * inv, g[koct * 4 + 1] * inv,
                                g[koct * 4 + 2] * inv, g[koct * 4 + 3] * inv);
            } else {
                *(ushort4*)((unsigned short*)zs_g + (size_t)node * 256 + arow * 16 + koct * 4) =
                    make_ushort4(f2bf(g[koct * 4] * inv), f2bf(g[koct * 4 + 1] * inv),
                                 f2bf(g[koct * 4 + 2] * inv), f2bf(g[koct * 4 + 3] * inv));
            }
            if (!uvalid) return;
            node = nnode; lo = nlo; hi = nhi; xrl = nxrl; xrh = nxrh;
            svbase = nlo; svall = nsvall; evall = nevall;
#pragma unroll
            for (int i = 0; i < 16; i++) g[i] = 0.f;
#pragma unroll
            for (int h = 0; h < 4; h++) dsum[h] = 0.f;
            nnode += STRIDE;
            nvalid = nnode < N_NODES;
            if (nvalid) {
                nlo = off[nnode]; nhi = off[nnode + 1];
                nxrl = *(const u16x8*)(xr_t + (size_t)nnode * 256 + arow * 16);
                nxrh = *(const u16x8*)(xr_t + (size_t)nnode * 256 + arow * 16 + 8);
                if (nhi > nlo) {
                    nsvall = csr_src[min(nlo + lane, nhi - 1)];
                    nevall = eid_csr[min(nlo + lane, nhi - 1)];
                }
            }
        }
        p0 = up0;
        if (EABF) af = __builtin_bit_cast(bf16x8, uAb);
        else af = pack_bf8(uA0, uA1);
#pragma unroll
        for (int r = 0; r < 4; r++) { xlo[r] = uxlo[r]; xhi[r] = uxhi[r]; }
        if (p0 - svbase >= 32) {
            svbase = p0;
            svall = csr_src[min(svbase + lane, hi - 1)];
            evall = eid_csr[min(svbase + lane, hi - 1)];
        }
    }
}

// ---------------- K6: MFMA epilogue (64 nodes/block, 4 waves x 16 nodes) ---
template<bool F32>
__global__ __launch_bounds__(256) void k_post(
    const void* __restrict__ zs_g, const float* __restrict__ x,
    const float* __restrict__ biasgp,
    const float* __restrict__ W1p, const float* __restrict__ b1p,
    const float* __restrict__ gammap, const float* __restrict__ betap,
    const float* __restrict__ W2p, const float* __restrict__ b2,
    float* __restrict__ out)
{
    __shared__ unsigned short wf[16384];        // 32 KB: w1f / w2f
    __shared__ unsigned short zsh[64][272];     // 34 KB
    __shared__ float outsh[64][64];             // 16 KB

    const int t = threadIdx.x, lane = t & 63, wv = t >> 6;
    const int arow = lane & 15, koct = lane >> 4;
    const int n0 = blockIdx.x * 64;
    const int nw = n0 + wv * 16;

    for (int i = t; i < 2048; i += 256) {
        const int ks = i >> 10, nt = (i >> 6) & 15, ls = i & 63;
        const int col = (ls & 15) * 16 + nt;
        const int kb = ks * 32 + (ls >> 4) * 8;
        unsigned short a[8];
#pragma unroll
        for (int j = 0; j < 8; j++) a[j] = f2bf(W1p[(kb + j) * 256 + col]);
        *(ushort4*)&wf[i * 8]     = make_ushort4(a[0], a[1], a[2], a[3]);
        *(ushort4*)&wf[i * 8 + 4] = make_ushort4(a[4], a[5], a[6], a[7]);
    }
    __syncthreads();

    const int xn = min(nw + arow, N_NODES - 1);
    const float* xrow = x + (size_t)xn * 64;
    const bf16x8 af0 = pack_bf8(*(const float4*)(xrow + koct * 8),
                                *(const float4*)(xrow + koct * 8 + 4));
    const bf16x8 af1 = pack_bf8(*(const float4*)(xrow + 32 + koct * 8),
                                *(const float4*)(xrow + 32 + koct * 8 + 4));

    float z[4][16];   // z[r][nt] = pos (arow*16 + nt) of node nw + koct*4 + r
#pragma unroll
    for (int nt = 0; nt < 16; nt++) {
        const float bv = b1p[arow * 16 + nt];
        f32x4 d = {bv, bv, bv, bv};
        d = __builtin_amdgcn_mfma_f32_16x16x32_bf16(af0, *(const bf16x8*)&wf[(0 * 16 + nt) * 512 + lane * 8], d, 0, 0, 0);
        d = __builtin_amdgcn_mfma_f32_16x16x32_bf16(af1, *(const bf16x8*)&wf[(1 * 16 + nt) * 512 + lane * 8], d, 0, 0, 0);
#pragma unroll
        for (int r = 0; r < 4; r++) z[r][nt] = d[r];
    }
#pragma unroll
    for (int r = 0; r < 4; r++) {
        const int nd = min(nw + koct * 4 + r, N_NODES - 1);
        float gv[16];
        if (F32) {
            const float* gp = (const float*)zs_g + (size_t)nd * 256 + arow * 16;
#pragma unroll
            for (int i4 = 0; i4 < 4; i4++) {
                const float4 v = *(const float4*)(gp + i4 * 4);
                gv[i4 * 4] = v.x; gv[i4 * 4 + 1] = v.y; gv[i4 * 4 + 2] = v.z; gv[i4 * 4 + 3] = v.w;
            }
        } else {
            const unsigned short* gp = (const unsigned short*)zs_g + (size_t)nd * 256 + arow * 16;
            const u16x8 a = *(const u16x8*)gp;
            const u16x8 b = *(const u16x8*)(gp + 8);
#pragma unroll
            for (int j = 0; j < 8; j++) { gv[j] = bf2f((unsigned short)a[j]); gv[j + 8] = bf2f((unsigned short)b[j]); }
        }
#pragma unroll
        for (int nt = 0; nt < 16; nt++)
            z[r][nt] = fast_tanh(z[r][nt]) + gv[nt] + biasgp[arow * 16 + nt];
    }
#pragma unroll
    for (int r = 0; r < 4; r++) {
        float s = 0.f, q = 0.f;
#pragma unroll
        for (int nt = 0; nt < 16; nt++) { s += z[r][nt]; q = fmaf(z[r][nt], z[r][nt], q); }
        s += __shfl_xor(s, 1, 64); q += __shfl_xor(q, 1, 64);
        s += __shfl_xor(s, 2, 64); q += __shfl_xor(q, 2, 64);
        s += __shfl_xor(s, 4, 64); q += __shfl_xor(q, 4, 64);
        s += __shfl_xor(s, 8, 64); q += __shfl_xor(q, 8, 64);
        const float mu = s * (1.f / 256.f);
        const float var = q * (1.f / 256.f) - mu * mu;
        const float ivn = rsqrtf(var + LN_EPS);
        u16x8 lo, hi;
#pragma unroll
        for (int nt = 0; nt < 16; nt++) {
            const float zn = (z[r][nt] - mu) * ivn * gammap[arow * 16 + nt] + betap[arow * 16 + nt];
            if (nt < 8) lo[nt] = f2bf(zn); else hi[nt - 8] = f2bf(zn);
        }
        unsigned short* dst = &zsh[wv * 16 + koct * 4 + r][arow * 16];
        *(u16x8*)dst = lo;
        *(u16x8*)(dst + 8) = hi;
    }
    __syncthreads();
    for (int i = t; i < 2048; i += 256) {
        const int kb = i >> 8, ct = (i >> 6) & 3, ls = i & 63;
        const int col = ct * 16 + (ls & 15);
        const int k0 = kb * 32 + (ls >> 4) * 8;
        unsigned short a[8];
#pragma unroll
        for (int j = 0; j < 8; j++) a[j] = f2bf(W2p[(k0 + j) * 64 + col]);
        *(ushort4*)&wf[i * 8]     = make_ushort4(a[0], a[1], a[2], a[3]);
        *(ushort4*)&wf[i * 8 + 4] = make_ushort4(a[4], a[5], a[6], a[7]);
    }
    __syncthreads();
    f32x4 acc2[4];
#pragma unroll
    for (int ct = 0; ct < 4; ct++) {
        const float bv = b2[ct * 16 + arow];
        acc2[ct][0] = bv; acc2[ct][1] = bv; acc2[ct][2] = bv; acc2[ct][3] = bv;
    }
#pragma unroll
    for (int kb = 0; kb < 8; kb++) {
        const bf16x8 a = *(const bf16x8*)&zsh[wv * 16 + arow][kb * 32 + koct * 8];
#pragma unroll
        for (int ct = 0; ct < 4; ct++)
            acc2[ct] = __builtin_amdgcn_mfma_f32_16x16x32_bf16(
                a, *(const bf16x8*)&wf[((kb * 4 + ct) * 64 + lane) * 8], acc2[ct], 0, 0, 0);
    }
#pragma unroll
    for (int ct = 0; ct < 4; ct++)
#pragma unroll
        for (int r = 0; r < 4; r++)
            outsh[wv * 16 + koct * 4 + r][ct * 16 + arow] = fast_tanh(acc2[ct][r]);
    __syncthreads();
    for (int i = t; i < 4096; i += 256) {
        const int row = i >> 6;
        if (n0 + row < N_NODES)
            out[(size_t)(n0 + row) * 64 + (i & 63)] = outsh[row][i & 63];
    }
}

// ---------------- launcher --------------------------------------------------
extern "C" void kernel_launch(void* const* d_in, const int* in_sizes, int n_in,
                              void* d_out, int out_size, void* d_ws, size_t ws_size,
                              hipStream_t stream)
{
    const float* x         = (const float*)d_in[0];
    const int*   ei        = (const int*)d_in[1];
    const float* edge_attr = (const float*)d_in[2];
    const float* W_l       = (const float*)d_in[3];
    const float* b_l       = (const float*)d_in[4];
    const float* W_r       = (const float*)d_in[5];
    const float* b_r       = (const float*)d_in[6];
    const float* W_e       = (const float*)d_in[7];
    const float* att       = (const float*)d_in[8];
    const float* bias_gat  = (const float*)d_in[9];
    const float* W1        = (const float*)d_in[10];
    const float* b1        = (const float*)d_in[11];
    const float* gamma     = (const float*)d_in[12];
    const float* beta      = (const float*)d_in[13];
    const float* W2        = (const float*)d_in[14];
    const float* b2        = (const float*)d_in[15];
    float* out = (float*)d_out;

    char* wsb = (char*)d_ws;
    size_t o = 0;
    unsigned short* xl_t   = (unsigned short*)(wsb + o);  o += (size_t)N_NODES * HC * 2;
    unsigned short* xr_t   = (unsigned short*)(wsb + o);  o += (size_t)N_NODES * HC * 2;
    int* csr_src           = (int*)(wsb + o);             o += (size_t)N_EDGES * 4;
    int* eid_csr           = (int*)(wsb + o);             o += (size_t)N_EDGES * 4;
    int* count             = (int*)(wsb + o);             o += (size_t)N_NODES * 4;
    int* cursor            = (int*)(wsb + o);             o += (size_t)N_NODES * 4;
    int* off               = (int*)(wsb + o);             o += (size_t)(N_NODES + 1) * 4;
    float* W1p             = (float*)(wsb + o);           o += 64 * 256 * 4;
    float* W2p             = (float*)(wsb + o);           o += 256 * 64 * 4;
    float* b1p             = (float*)(wsb + o);           o += 256 * 4;
    float* gammap          = (float*)(wsb + o);           o += 256 * 4;
    float* betap           = (float*)(wsb + o);           o += 256 * 4;
    float* biasgp          = (float*)(wsb + o);           o += 256 * 4;
    o = (o + 255) & ~(size_t)255;
    void* zs_g             = (void*)(wsb + o);
    const size_t zs_f32_bytes = (size_t)N_NODES * HC * 4;
    const size_t ea_bytes     = (size_t)N_EDGES * 32 * 2;
    const bool f32ok = (o + zs_f32_bytes) <= ws_size;
    size_t o_ea = o + (f32ok ? zs_f32_bytes : (size_t)N_NODES * HC * 2);
    o_ea = (o_ea + 255) & ~(size_t)255;
    const bool eaok = (o_ea + ea_bytes) <= ws_size;
    unsigned short* ea_bf = (unsigned short*)(wsb + o_ea);

    hipMemsetAsync(count, 0, 2 * (size_t)N_NODES * sizeof(int), stream);

    k_ntm<<<NTM_BLOCKS, 256, 0, stream>>>(x, W_l, b_l, W_r, b_r,
                                          ei, count, edge_attr, ea_bf, eaok ? 1 : 0,
                                          W1, b1, gamma, beta, bias_gat, W2,
                                          W1p, b1p, gammap, betap, biasgp, W2p,
                                          xl_t, xr_t);
    k_scan<<<1, 1024, 0, stream>>>(count, off);
    k_scatter<<<(N_EDGES + 255) / 256, 256, 0, stream>>>(ei, off, cursor, csr_src, eid_csr);
    if (f32ok && eaok) {
        k_edgeagg<true, true><<<EDGE_BLOCKS, 256, 0, stream>>>(off, csr_src, eid_csr, edge_attr,
                                                               ea_bf, W_e, att, xl_t, xr_t, zs_g);
        k_post<true><<<(N_NODES + 63) / 64, 256, 0, stream>>>(zs_g, x, biasgp,
                                                              W1p, b1p, gammap, betap, W2p, b2, out);
    } else if (f32ok) {
        k_edgeagg<true, false><<<EDGE_BLOCKS, 256, 0, stream>>>(off, csr_src, eid_csr, edge_attr,
                                                                ea_bf, W_e, att, xl_t, xr_t, zs_g);
        k_post<true><<<(N_NODES + 63) / 64, 256, 0, stream>>>(zs_g, x, biasgp,
                                                              W1p, b1p, gammap, betap, W2p, b2, out);
    } else {
        k_edgeagg<false, false><<<EDGE_BLOCKS, 256, 0, stream>>>(off, csr_src, eid_csr, edge_attr,
                                                                 ea_bf, W_e, att, xl_t, xr_t, zs_g);
        k_post<false><<<(N_NODES + 63) / 64, 256, 0, stream>>>(zs_g, x, biasgp,
                                                               W1p, b1p, gammap, betap, W2p, b2, out);
    }
}

// Round 23
// 523.618 us; speedup vs baseline: 1.0350x; 1.0350x over previous
//
#include <hip/hip_runtime.h>
#include <math.h>

#define N_NODES 50000
#define N_EDGES 800000
#define HID 64
#define HEADS 4
#define HC 256
#define NEG_SLOPE 0.2f
#define LN_EPS 1e-5f
#define EDGE_BLOCKS 2048   // persistent-wave grid for k_edgeagg (8192 waves)
#define NTM_BLOCKS 782     // ceil(50000/64); hist slice sized to cover edges

typedef __attribute__((ext_vector_type(8))) short bf16x8;
typedef __attribute__((ext_vector_type(8))) unsigned short u16x8;
typedef __attribute__((ext_vector_type(4))) float f32x4;

__device__ __forceinline__ float bf2f(unsigned short u) {
    return __uint_as_float(((unsigned int)u) << 16);
}
__device__ __forceinline__ unsigned short f2bf(float f) {
    unsigned int u = __float_as_uint(f);
    u = (u + 0x7fffu + ((u >> 16) & 1u)) >> 16;   // RNE
    return (unsigned short)u;
}
__device__ __forceinline__ float fast_tanh(float v) {
    const float c = fminf(fmaxf(v, -15.f), 15.f);
    const float e = __expf(2.f * c);
    return 1.f - 2.f / (e + 1.f);
}
__device__ __forceinline__ bf16x8 pack_bf8(float4 a, float4 b) {
    u16x8 r;
    r[0] = f2bf(a.x); r[1] = f2bf(a.y); r[2] = f2bf(a.z); r[3] = f2bf(a.w);
    r[4] = f2bf(b.x); r[5] = f2bf(b.y); r[6] = f2bf(b.z); r[7] = f2bf(b.w);
    return __builtin_bit_cast(bf16x8, r);
}

// ---------------- K1: MFMA node transform + fused hist + permw -------------
__global__ __launch_bounds__(256) void k_ntm(
    const float* __restrict__ x,
    const float* __restrict__ W_l, const float* __restrict__ b_l,
    const float* __restrict__ W_r, const float* __restrict__ b_r,
    const int* __restrict__ ei, int* __restrict__ count,
    const float* __restrict__ W1, const float* __restrict__ b1,
    const float* __restrict__ gamma, const float* __restrict__ beta,
    const float* __restrict__ bias_gat, const float* __restrict__ W2,
    float* __restrict__ W1p, float* __restrict__ b1p,
    float* __restrict__ gammap, float* __restrict__ betap,
    float* __restrict__ biasgp, float* __restrict__ W2p,
    unsigned short* __restrict__ xl_t, unsigned short* __restrict__ xr_t)
{
    __shared__ unsigned short wl_s[2][16][64][8];   // 32 KB
    __shared__ unsigned short wr_s[2][16][64][8];   // 32 KB
    const int t = threadIdx.x, lane = t & 63, wv = t >> 6;
    const int arow = lane & 15, koct = lane >> 4;
    const int bid = blockIdx.x;

    // ---- hist slice (fire-and-forget atomics; 1024 edges/block covers all) --
    {
        const int e0 = bid * 1024;
#pragma unroll
        for (int j = 0; j < 4; j++) {
            const int e = e0 + j * 256 + t;
            if (e < N_EDGES) atomicAdd(&count[ei[N_EDGES + e]], 1);
        }
    }
    // ---- permw slice (last block only) ----
    if (bid == NTM_BLOCKS - 1) {
        const int c = t;
        const int pos = (c & 15) * 16 + (c >> 4);
        for (int k = 0; k < 64; k++) W1p[k * 256 + pos] = W1[k * 256 + c];
        b1p[pos] = b1[c];
        gammap[pos] = gamma[c];
        betap[pos] = beta[c];
        biasgp[pos] = bias_gat[c];
        for (int j = 0; j < 64; j++) W2p[pos * 64 + j] = W2[c * 64 + j];
    }

    // ---- W staging ----
    for (int i = t; i < 2048; i += 256) {
        const int ks = i >> 10, nt = (i >> 6) & 15, ls = i & 63;
        const int col = nt * 16 + (ls & 15);
        const int kb = ks * 32 + (ls >> 4) * 8;
        unsigned short a[8], b[8];
#pragma unroll
        for (int j = 0; j < 8; j++) {
            a[j] = f2bf(W_l[(kb + j) * 256 + col]);
            b[j] = f2bf(W_r[(kb + j) * 256 + col]);
        }
        *(ushort4*)&wl_s[ks][nt][ls][0] = make_ushort4(a[0], a[1], a[2], a[3]);
        *(ushort4*)&wl_s[ks][nt][ls][4] = make_ushort4(a[4], a[5], a[6], a[7]);
        *(ushort4*)&wr_s[ks][nt][ls][0] = make_ushort4(b[0], b[1], b[2], b[3]);
        *(ushort4*)&wr_s[ks][nt][ls][4] = make_ushort4(b[4], b[5], b[6], b[7]);
    }
    __syncthreads();

    const int n0w = bid * 64 + wv * 16;
    if (n0w >= N_NODES) return;

    const float* xrow = x + (size_t)(n0w + arow) * 64;
    const bf16x8 af0 = pack_bf8(*(const float4*)(xrow + koct * 8),
                                *(const float4*)(xrow + koct * 8 + 4));
    const bf16x8 af1 = pack_bf8(*(const float4*)(xrow + 32 + koct * 8),
                                *(const float4*)(xrow + 32 + koct * 8 + 4));

    float acc[4][16];
#pragma unroll
    for (int nt = 0; nt < 16; nt++) {
        const float bv = b_l[nt * 16 + arow];
        f32x4 d = {bv, bv, bv, bv};
        d = __builtin_amdgcn_mfma_f32_16x16x32_bf16(af0, *(const bf16x8*)&wl_s[0][nt][lane][0], d, 0, 0, 0);
        d = __builtin_amdgcn_mfma_f32_16x16x32_bf16(af1, *(const bf16x8*)&wl_s[1][nt][lane][0], d, 0, 0, 0);
#pragma unroll
        for (int r = 0; r < 4; r++) acc[r][nt] = d[r];
    }
#pragma unroll
    for (int r = 0; r < 4; r++) {
        u16x8 lo, hi;
#pragma unroll
        for (int j = 0; j < 8; j++) { lo[j] = f2bf(acc[r][j]); hi[j] = f2bf(acc[r][j + 8]); }
        unsigned short* dst = xl_t + (size_t)(n0w + koct * 4 + r) * 256 + arow * 16;
        *(u16x8*)dst = lo;
        *(u16x8*)(dst + 8) = hi;
    }
#pragma unroll
    for (int nt = 0; nt < 16; nt++) {
        const float bv = b_r[nt * 16 + arow];
        f32x4 d = {bv, bv, bv, bv};
        d = __builtin_amdgcn_mfma_f32_16x16x32_bf16(af0, *(const bf16x8*)&wr_s[0][nt][lane][0], d, 0, 0, 0);
        d = __builtin_amdgcn_mfma_f32_16x16x32_bf16(af1, *(const bf16x8*)&wr_s[1][nt][lane][0], d, 0, 0, 0);
#pragma unroll
        for (int r = 0; r < 4; r++) acc[r][nt] = d[r];
    }
#pragma unroll
    for (int r = 0; r < 4; r++) {
        u16x8 lo, hi;
#pragma unroll
        for (int j = 0; j < 8; j++) { lo[j] = f2bf(acc[r][j]); hi[j] = f2bf(acc[r][j + 8]); }
        unsigned short* dst = xr_t + (size_t)(n0w + koct * 4 + r) * 256 + arow * 16;
        *(u16x8*)dst = lo;
        *(u16x8*)(dst + 8) = hi;
    }
}

// ---------------- K3: exclusive scan (single block) ------------------------
__global__ __launch_bounds__(1024) void k_scan(const int* __restrict__ count, int* __restrict__ off)
{
    __shared__ int wsum[16];
    __shared__ int s_carry;
    const int t = threadIdx.x, lane = t & 63, wv = t >> 6;
    if (t == 0) s_carry = 0;
    __syncthreads();
    for (int base = 0; base < N_NODES; base += 8192) {
        const int idx0 = base + t * 8;
        int v[8];
#pragma unroll
        for (int j = 0; j < 8; j++) { int i = idx0 + j; v[j] = (i < N_NODES) ? count[i] : 0; }
#pragma unroll
        for (int j = 1; j < 8; j++) v[j] += v[j - 1];
        const int tot = v[7];
        int sc = tot;
#pragma unroll
        for (int s = 1; s < 64; s <<= 1) { int o = __shfl_up(sc, s, 64); if (lane >= s) sc += o; }
        if (lane == 63) wsum[wv] = sc;
        __syncthreads();
        const int carry = s_carry;
        int woff = 0;
        for (int u = 0; u < wv; u++) woff += wsum[u];
        const int ebase = carry + woff + (sc - tot);
#pragma unroll
        for (int j = 0; j < 8; j++) {
            int i = idx0 + j;
            if (i < N_NODES) off[i] = ebase + (j ? v[j - 1] : 0);
        }
        __syncthreads();
        if (t == 0) { int tt = 0; for (int u = 0; u < 16; u++) tt += wsum[u]; s_carry = carry + tt; }
        __syncthreads();
    }
    if (threadIdx.x == 0) off[N_NODES] = s_carry;
}

// ---------------- K4: scatter src/eid + ea->bf16 convert -------------------
// Thread e already exists for the scatter; the coalesced edge_attr convert
// rides under the atomic-latency-bound waves.
__global__ __launch_bounds__(256) void k_scatter(
    const int* __restrict__ ei, const int* __restrict__ off, int* __restrict__ cursor,
    const float* __restrict__ edge_attr, unsigned short* __restrict__ ea_bf,
    const int do_ea,
    int* __restrict__ csr_src, int* __restrict__ eid_csr)
{
    const int e = blockIdx.x * 256 + threadIdx.x;
    if (e < N_EDGES) {
        const int s = ei[e];
        const int d = ei[N_EDGES + e];
        const int pos = off[d] + atomicAdd(&cursor[d], 1);
        csr_src[pos] = s;
        eid_csr[pos] = e;
        if (do_ea) {
            const float4* src4 = (const float4*)(edge_attr + (size_t)e * 32);
            ushort4* dst4 = (ushort4*)(ea_bf + (size_t)e * 32);
#pragma unroll
            for (int i = 0; i < 8; i += 2) {
                const float4 v0 = src4[i], v1 = src4[i + 1];
                dst4[i]     = make_ushort4(f2bf(v0.x), f2bf(v0.y), f2bf(v0.z), f2bf(v0.w));
                dst4[i + 1] = make_ushort4(f2bf(v1.x), f2bf(v1.y), f2bf(v1.z), f2bf(v1.w));
            }
        }
    }
}

// ---------------- K5: edge+aggregate, persistent waves, deep pipeline ------
// EABF: A-frags loaded directly from pre-converted bf16 ea_bf (16B/lane).
template<bool F32, bool EABF>
__global__ __launch_bounds__(256) void k_edgeagg(
    const int* __restrict__ off, const int* __restrict__ csr_src,
    const int* __restrict__ eid_csr, const float* __restrict__ edge_attr,
    const unsigned short* __restrict__ ea_bf,
    const float* __restrict__ W_e, const float* __restrict__ att,
    const unsigned short* __restrict__ xl_t, const unsigned short* __restrict__ xr_t,
    void* __restrict__ zs_g)
{
    __shared__ unsigned short bfrag_s[16][64][8];   // 16 KB, only LDS

    const int t = threadIdx.x;
    const int lane = t & 63, wv = t >> 6;
    const int arow = lane & 15, koct = lane >> 4;

    for (int i = t; i < 1024; i += 256) {
        const int nt = i >> 6, ls = i & 63;
        const int col = nt * 16 + (ls & 15);
        const int kb = (ls >> 4) * 8;
        unsigned short tmp[8];
#pragma unroll
        for (int j = 0; j < 8; j++) tmp[j] = f2bf(W_e[(kb + j) * 256 + col]);
        *(ushort4*)&bfrag_s[nt][ls][0] = make_ushort4(tmp[0], tmp[1], tmp[2], tmp[3]);
        *(ushort4*)&bfrag_s[nt][ls][4] = make_ushort4(tmp[4], tmp[5], tmp[6], tmp[7]);
    }
    __syncthreads();

    float attLf[8], attHf[8];
#pragma unroll
    for (int j = 0; j < 8; j++) {
        attLf[j] = att[j * 16 + arow];
        attHf[j] = att[(j + 8) * 16 + arow];
    }

    const int STRIDE = EDGE_BLOCKS * 4;
    int node = blockIdx.x * 4 + wv;
    if (node >= N_NODES) return;

    int lo = off[node], hi = off[node + 1];
    u16x8 xrl = *(const u16x8*)(xr_t + (size_t)node * 256 + arow * 16);
    u16x8 xrh = *(const u16x8*)(xr_t + (size_t)node * 256 + arow * 16 + 8);
    while (hi <= lo) {
        if (F32) *(float4*)((float*)zs_g + (size_t)node * 256 + arow * 16 + koct * 4) = make_float4(0.f, 0.f, 0.f, 0.f);
        else *(ushort4*)((unsigned short*)zs_g + (size_t)node * 256 + arow * 16 + koct * 4) = make_ushort4(0, 0, 0, 0);
        node += STRIDE;
        if (node >= N_NODES) return;
        lo = off[node]; hi = off[node + 1];
        xrl = *(const u16x8*)(xr_t + (size_t)node * 256 + arow * 16);
        xrh = *(const u16x8*)(xr_t + (size_t)node * 256 + arow * 16 + 8);
    }
    int svbase = lo;
    int svall = csr_src[min(svbase + lane, hi - 1)];
    int evall = eid_csr[min(svbase + lane, hi - 1)];

    int nnode = node + STRIDE;
    bool nvalid = nnode < N_NODES;
    int nlo = 0, nhi = 0, nsvall = 0, nevall = 0;
    u16x8 nxrl = xrl, nxrh = xrh;
    if (nvalid) {
        nlo = off[nnode]; nhi = off[nnode + 1];
        nxrl = *(const u16x8*)(xr_t + (size_t)nnode * 256 + arow * 16);
        nxrh = *(const u16x8*)(xr_t + (size_t)nnode * 256 + arow * 16 + 8);
        if (nhi > nlo) {
            nsvall = csr_src[min(nlo + lane, nhi - 1)];
            nevall = eid_csr[min(nlo + lane, nhi - 1)];
        }
    }
    int p0 = lo;
    bf16x8 af;
    u16x8 xlo[4], xhi[4];
    {
        const int eid0 = __shfl(evall, arow, 64);
        if (EABF) {
            af = *(const bf16x8*)(ea_bf + (size_t)eid0 * 32 + koct * 8);
        } else {
            const float* ap = edge_attr + (size_t)eid0 * 32 + koct * 8;
            af = pack_bf8(*(const float4*)ap, *(const float4*)(ap + 4));
        }
#pragma unroll
        for (int r = 0; r < 4; r++) {
            const int sr = __shfl(svall, koct * 4 + r, 64);
            const unsigned short* bp = xl_t + (size_t)sr * 256 + arow * 16;
            xlo[r] = *(const u16x8*)bp;
            xhi[r] = *(const u16x8*)(bp + 8);
        }
    }

    float g[16];
#pragma unroll
    for (int i = 0; i < 16; i++) g[i] = 0.f;
    float dsum[4] = {0.f, 0.f, 0.f, 0.f};

    for (;;) {
        const bool last = (p0 + 16 >= hi);
        bool uvalid;
        int up0;
        if (!last) { uvalid = true; up0 = p0 + 16; }
        else {
            while (nvalid && nlo >= nhi) {
                if (F32) *(float4*)((float*)zs_g + (size_t)nnode * 256 + arow * 16 + koct * 4) = make_float4(0.f, 0.f, 0.f, 0.f);
                else *(ushort4*)((unsigned short*)zs_g + (size_t)nnode * 256 + arow * 16 + koct * 4) = make_ushort4(0, 0, 0, 0);
                nnode += STRIDE;
                nvalid = nnode < N_NODES;
                if (nvalid) {
                    nlo = off[nnode]; nhi = off[nnode + 1];
                    nxrl = *(const u16x8*)(xr_t + (size_t)nnode * 256 + arow * 16);
                    nxrh = *(const u16x8*)(xr_t + (size_t)nnode * 256 + arow * 16 + 8);
                    if (nhi > nlo) {
                        nsvall = csr_src[min(nlo + lane, nhi - 1)];
                        nevall = eid_csr[min(nlo + lane, nhi - 1)];
                    }
                }
            }
            uvalid = nvalid; up0 = nlo;
        }
        u16x8 uAb = {0, 0, 0, 0, 0, 0, 0, 0};
        float4 uA0 = make_float4(0.f, 0.f, 0.f, 0.f), uA1 = uA0;
        if (uvalid) {
            const int ubase = last ? 0 : (up0 - svbase);
            const int uev = last ? nevall : evall;
            const int ueid = __shfl(uev, ubase + arow, 64);
            if (EABF) {
                uAb = *(const u16x8*)(ea_bf + (size_t)ueid * 32 + koct * 8);
            } else {
                const float* ap = edge_attr + (size_t)ueid * 32 + koct * 8;
                uA0 = *(const float4*)ap;
                uA1 = *(const float4*)(ap + 4);
            }
        }

        float s_[4][4];
#pragma unroll
        for (int r = 0; r < 4; r++)
#pragma unroll
            for (int h = 0; h < 4; h++) s_[r][h] = 0.f;

#pragma unroll
        for (int nt = 0; nt < 8; nt++) {
            const bf16x8 bfr = *(const bf16x8*)&bfrag_s[nt][lane][0];
            const float xrv = bf2f((unsigned short)xrl[nt]);
            f32x4 dacc = {xrv, xrv, xrv, xrv};
            dacc = __builtin_amdgcn_mfma_f32_16x16x32_bf16(af, bfr, dacc, 0, 0, 0);
            const float atv = attLf[nt];
            const int h = nt >> 2;
#pragma unroll
            for (int r = 0; r < 4; r++) {
                const float mm = dacc[r] + bf2f((unsigned short)xlo[r][nt]);
                const float lk = fmaxf(mm, NEG_SLOPE * mm);
                s_[r][h] = fmaf(atv, lk, s_[r][h]);
            }
        }
        u16x8 uxlo[4], uxhi[4];
        if (uvalid) {
            const int ubase = last ? 0 : (up0 - svbase);
            const int usrcv = last ? nsvall : svall;
#pragma unroll
            for (int r = 0; r < 4; r++) {
                const int sr = __shfl(usrcv, ubase + koct * 4 + r, 64);
                const unsigned short* bp = xl_t + (size_t)sr * 256 + arow * 16;
                uxlo[r] = *(const u16x8*)bp;
                uxhi[r] = *(const u16x8*)(bp + 8);
            }
        } else {
#pragma unroll
            for (int r = 0; r < 4; r++) { uxlo[r] = xlo[r]; uxhi[r] = xhi[r]; }
        }
#pragma unroll
        for (int n2 = 0; n2 < 8; n2++) {
            const int nt = n2 + 8;
            const bf16x8 bfr = *(const bf16x8*)&bfrag_s[nt][lane][0];
            const float xrv = bf2f((unsigned short)xrh[n2]);
            f32x4 dacc = {xrv, xrv, xrv, xrv};
            dacc = __builtin_amdgcn_mfma_f32_16x16x32_bf16(af, bfr, dacc, 0, 0, 0);
            const float atv = attHf[n2];
            const int h = nt >> 2;
#pragma unroll
            for (int r = 0; r < 4; r++) {
                const float mm = dacc[r] + bf2f((unsigned short)xhi[r][n2]);
                const float lk = fmaxf(mm, NEG_SLOPE * mm);
                s_[r][h] = fmaf(atv, lk, s_[r][h]);
            }
        }
#pragma unroll
        for (int r = 0; r < 4; r++)
#pragma unroll
            for (int h = 0; h < 4; h++) {
                float v = s_[r][h];
                v += __shfl_xor(v, 1, 64);
                v += __shfl_xor(v, 2, 64);
                v += __shfl_xor(v, 4, 64);
                v += __shfl_xor(v, 8, 64);
                s_[r][h] = v;
            }
#pragma unroll
        for (int h = 0; h < 4; h++) {
            float w4[4];
#pragma unroll
            for (int r = 0; r < 4; r++) {
                const bool ok = (p0 + koct * 4 + r) < hi;
                w4[r] = ok ? __expf(fminf(s_[r][h], 60.f)) : 0.f;
            }
            dsum[h] += (w4[0] + w4[1]) + (w4[2] + w4[3]);
#pragma unroll
            for (int q = 0; q < 4; q++) {
                const int nt = h * 4 + q;
                float acc = g[nt];
#pragma unroll
                for (int r = 0; r < 4; r++) {
                    const float xv = bf2f((unsigned short)(nt < 8 ? xlo[r][nt & 7] : xhi[r][nt & 7]));
                    acc = fmaf(w4[r], xv, acc);
                }
                g[nt] = acc;
            }
        }

        if (last) {
#pragma unroll
            for (int i = 0; i < 16; i++) {
                float v = g[i];
                v += __shfl_xor(v, 16, 64);
                v += __shfl_xor(v, 32, 64);
                g[i] = v;
            }
#pragma unroll
            for (int h = 0; h < 4; h++) {
                float v = dsum[h];
                v += __shfl_xor(v, 16, 64);
                v += __shfl_xor(v, 32, 64);
                dsum[h] = v;
            }
            const float inv = 1.f / (dsum[koct] + 1e-16f);
            if (F32) {
                *(float4*)((float*)zs_g + (size_t)node * 256 + arow * 16 + koct * 4) =
                    make_float4(g[koct * 4] * inv, g[koct * 4 + 1] * inv,
                                g[koct * 4 + 2] * inv, g[koct * 4 + 3] * inv);
            } else {
                *(ushort4*)((unsigned short*)zs_g + (size_t)node * 256 + arow * 16 + koct * 4) =
                    make_ushort4(f2bf(g[koct * 4] * inv), f2bf(g[koct * 4 + 1] * inv),
                                 f2bf(g[koct * 4 + 2] * inv), f2bf(g[koct * 4 + 3] * inv));
            }
            if (!uvalid) return;
            node = nnode; lo = nlo; hi = nhi; xrl = nxrl; xrh = nxrh;
            svbase = nlo; svall = nsvall; evall = nevall;
#pragma unroll
            for (int i = 0; i < 16; i++) g[i] = 0.f;
#pragma unroll
            for (int h = 0; h < 4; h++) dsum[h] = 0.f;
            nnode += STRIDE;
            nvalid = nnode < N_NODES;
            if (nvalid) {
                nlo = off[nnode]; nhi = off[nnode + 1];
                nxrl = *(const u16x8*)(xr_t + (size_t)nnode * 256 + arow * 16);
                nxrh = *(const u16x8*)(xr_t + (size_t)nnode * 256 + arow * 16 + 8);
                if (nhi > nlo) {
                    nsvall = csr_src[min(nlo + lane, nhi - 1)];
                    nevall = eid_csr[min(nlo + lane, nhi - 1)];
                }
            }
        }
        p0 = up0;
        if (EABF) af = __builtin_bit_cast(bf16x8, uAb);
        else af = pack_bf8(uA0, uA1);
#pragma unroll
        for (int r = 0; r < 4; r++) { xlo[r] = uxlo[r]; xhi[r] = uxhi[r]; }
        if (p0 - svbase >= 32) {
            svbase = p0;
            svall = csr_src[min(svbase + lane, hi - 1)];
            evall = eid_csr[min(svbase + lane, hi - 1)];
        }
    }
}

// ---------------- K6: MFMA epilogue (64 nodes/block, 4 waves x 16 nodes) ---
template<bool F32>
__global__ __launch_bounds__(256) void k_post(
    const void* __restrict__ zs_g, const float* __restrict__ x,
    const float* __restrict__ biasgp,
    const float* __restrict__ W1p, const float* __restrict__ b1p,
    const float* __restrict__ gammap, const float* __restrict__ betap,
    const float* __restrict__ W2p, const float* __restrict__ b2,
    float* __restrict__ out)
{
    __shared__ unsigned short wf[16384];        // 32 KB: w1f / w2f
    __shared__ unsigned short zsh[64][272];     // 34 KB
    __shared__ float outsh[64][64];             // 16 KB

    const int t = threadIdx.x, lane = t & 63, wv = t >> 6;
    const int arow = lane & 15, koct = lane >> 4;
    const int n0 = blockIdx.x * 64;
    const int nw = n0 + wv * 16;

    for (int i = t; i < 2048; i += 256) {
        const int ks = i >> 10, nt = (i >> 6) & 15, ls = i & 63;
        const int col = (ls & 15) * 16 + nt;
        const int kb = ks * 32 + (ls >> 4) * 8;
        unsigned short a[8];
#pragma unroll
        for (int j = 0; j < 8; j++) a[j] = f2bf(W1p[(kb + j) * 256 + col]);
        *(ushort4*)&wf[i * 8]     = make_ushort4(a[0], a[1], a[2], a[3]);
        *(ushort4*)&wf[i * 8 + 4] = make_ushort4(a[4], a[5], a[6], a[7]);
    }
    __syncthreads();

    const int xn = min(nw + arow, N_NODES - 1);
    const float* xrow = x + (size_t)xn * 64;
    const bf16x8 af0 = pack_bf8(*(const float4*)(xrow + koct * 8),
                                *(const float4*)(xrow + koct * 8 + 4));
    const bf16x8 af1 = pack_bf8(*(const float4*)(xrow + 32 + koct * 8),
                                *(const float4*)(xrow + 32 + koct * 8 + 4));

    float z[4][16];   // z[r][nt] = pos (arow*16 + nt) of node nw + koct*4 + r
#pragma unroll
    for (int nt = 0; nt < 16; nt++) {
        const float bv = b1p[arow * 16 + nt];
        f32x4 d = {bv, bv, bv, bv};
        d = __builtin_amdgcn_mfma_f32_16x16x32_bf16(af0, *(const bf16x8*)&wf[(0 * 16 + nt) * 512 + lane * 8], d, 0, 0, 0);
        d = __builtin_amdgcn_mfma_f32_16x16x32_bf16(af1, *(const bf16x8*)&wf[(1 * 16 + nt) * 512 + lane * 8], d, 0, 0, 0);
#pragma unroll
        for (int r = 0; r < 4; r++) z[r][nt] = d[r];
    }
#pragma unroll
    for (int r = 0; r < 4; r++) {
        const int nd = min(nw + koct * 4 + r, N_NODES - 1);
        float gv[16];
        if (F32) {
            const float* gp = (const float*)zs_g + (size_t)nd * 256 + arow * 16;
#pragma unroll
            for (int i4 = 0; i4 < 4; i4++) {
                const float4 v = *(const float4*)(gp + i4 * 4);
                gv[i4 * 4] = v.x; gv[i4 * 4 + 1] = v.y; gv[i4 * 4 + 2] = v.z; gv[i4 * 4 + 3] = v.w;
            }
        } else {
            const unsigned short* gp = (const unsigned short*)zs_g + (size_t)nd * 256 + arow * 16;
            const u16x8 a = *(const u16x8*)gp;
            const u16x8 b = *(const u16x8*)(gp + 8);
#pragma unroll
            for (int j = 0; j < 8; j++) { gv[j] = bf2f((unsigned short)a[j]); gv[j + 8] = bf2f((unsigned short)b[j]); }
        }
#pragma unroll
        for (int nt = 0; nt < 16; nt++)
            z[r][nt] = fast_tanh(z[r][nt]) + gv[nt] + biasgp[arow * 16 + nt];
    }
#pragma unroll
    for (int r = 0; r < 4; r++) {
        float s = 0.f, q = 0.f;
#pragma unroll
        for (int nt = 0; nt < 16; nt++) { s += z[r][nt]; q = fmaf(z[r][nt], z[r][nt], q); }
        s += __shfl_xor(s, 1, 64); q += __shfl_xor(q, 1, 64);
        s += __shfl_xor(s, 2, 64); q += __shfl_xor(q, 2, 64);
        s += __shfl_xor(s, 4, 64); q += __shfl_xor(q, 4, 64);
        s += __shfl_xor(s, 8, 64); q += __shfl_xor(q, 8, 64);
        const float mu = s * (1.f / 256.f);
        const float var = q * (1.f / 256.f) - mu * mu;
        const float ivn = rsqrtf(var + LN_EPS);
        u16x8 lo, hi;
#pragma unroll
        for (int nt = 0; nt < 16; nt++) {
            const float zn = (z[r][nt] - mu) * ivn * gammap[arow * 16 + nt] + betap[arow * 16 + nt];
            if (nt < 8) lo[nt] = f2bf(zn); else hi[nt - 8] = f2bf(zn);
        }
        unsigned short* dst = &zsh[wv * 16 + koct * 4 + r][arow * 16];
        *(u16x8*)dst = lo;
        *(u16x8*)(dst + 8) = hi;
    }
    __syncthreads();
    for (int i = t; i < 2048; i += 256) {
        const int kb = i >> 8, ct = (i >> 6) & 3, ls = i & 63;
        const int col = ct * 16 + (ls & 15);
        const int k0 = kb * 32 + (ls >> 4) * 8;
        unsigned short a[8];
#pragma unroll
        for (int j = 0; j < 8; j++) a[j] = f2bf(W2p[(k0 + j) * 64 + col]);
        *(ushort4*)&wf[i * 8]     = make_ushort4(a[0], a[1], a[2], a[3]);
        *(ushort4*)&wf[i * 8 + 4] = make_ushort4(a[4], a[5], a[6], a[7]);
    }
    __syncthreads();
    f32x4 acc2[4];
#pragma unroll
    for (int ct = 0; ct < 4; ct++) {
        const float bv = b2[ct * 16 + arow];
        acc2[ct][0] = bv; acc2[ct][1] = bv; acc2[ct][2] = bv; acc2[ct][3] = bv;
    }
#pragma unroll
    for (int kb = 0; kb < 8; kb++) {
        const bf16x8 a = *(const bf16x8*)&zsh[wv * 16 + arow][kb * 32 + koct * 8];
#pragma unroll
        for (int ct = 0; ct < 4; ct++)
            acc2[ct] = __builtin_amdgcn_mfma_f32_16x16x32_bf16(
                a, *(const bf16x8*)&wf[((kb * 4 + ct) * 64 + lane) * 8], acc2[ct], 0, 0, 0);
    }
#pragma unroll
    for (int ct = 0; ct < 4; ct++)
#pragma unroll
        for (int r = 0; r < 4; r++)
            outsh[wv * 16 + koct * 4 + r][ct * 16 + arow] = fast_tanh(acc2[ct][r]);
    __syncthreads();
    for (int i = t; i < 4096; i += 256) {
        const int row = i >> 6;
        if (n0 + row < N_NODES)
            out[(size_t)(n0 + row) * 64 + (i & 63)] = outsh[row][i & 63];
    }
}

// ---------------- launcher --------------------------------------------------
extern "C" void kernel_launch(void* const* d_in, const int* in_sizes, int n_in,
                              void* d_out, int out_size, void* d_ws, size_t ws_size,
                              hipStream_t stream)
{
    const float* x         = (const float*)d_in[0];
    const int*   ei        = (const int*)d_in[1];
    const float* edge_attr = (const float*)d_in[2];
    const float* W_l       = (const float*)d_in[3];
    const float* b_l       = (const float*)d_in[4];
    const float* W_r       = (const float*)d_in[5];
    const float* b_r       = (const float*)d_in[6];
    const float* W_e       = (const float*)d_in[7];
    const float* att       = (const float*)d_in[8];
    const float* bias_gat  = (const float*)d_in[9];
    const float* W1        = (const float*)d_in[10];
    const float* b1        = (const float*)d_in[11];
    const float* gamma     = (const float*)d_in[12];
    const float* beta      = (const float*)d_in[13];
    const float* W2        = (const float*)d_in[14];
    const float* b2        = (const float*)d_in[15];
    float* out = (float*)d_out;

    char* wsb = (char*)d_ws;
    size_t o = 0;
    unsigned short* xl_t   = (unsigned short*)(wsb + o);  o += (size_t)N_NODES * HC * 2;
    unsigned short* xr_t   = (unsigned short*)(wsb + o);  o += (size_t)N_NODES * HC * 2;
    int* csr_src           = (int*)(wsb + o);             o += (size_t)N_EDGES * 4;
    int* eid_csr           = (int*)(wsb + o);             o += (size_t)N_EDGES * 4;
    int* count             = (int*)(wsb + o);             o += (size_t)N_NODES * 4;
    int* cursor            = (int*)(wsb + o);             o += (size_t)N_NODES * 4;
    int* off               = (int*)(wsb + o);             o += (size_t)(N_NODES + 1) * 4;
    float* W1p             = (float*)(wsb + o);           o += 64 * 256 * 4;
    float* W2p             = (float*)(wsb + o);           o += 256 * 64 * 4;
    float* b1p             = (float*)(wsb + o);           o += 256 * 4;
    float* gammap          = (float*)(wsb + o);           o += 256 * 4;
    float* betap           = (float*)(wsb + o);           o += 256 * 4;
    float* biasgp          = (float*)(wsb + o);           o += 256 * 4;
    o = (o + 255) & ~(size_t)255;
    void* zs_g             = (void*)(wsb + o);
    const size_t zs_f32_bytes = (size_t)N_NODES * HC * 4;
    const size_t ea_bytes     = (size_t)N_EDGES * 32 * 2;
    const bool f32ok = (o + zs_f32_bytes) <= ws_size;
    size_t o_ea = o + (f32ok ? zs_f32_bytes : (size_t)N_NODES * HC * 2);
    o_ea = (o_ea + 255) & ~(size_t)255;
    const bool eaok = (o_ea + ea_bytes) <= ws_size;
    unsigned short* ea_bf = (unsigned short*)(wsb + o_ea);

    hipMemsetAsync(count, 0, 2 * (size_t)N_NODES * sizeof(int), stream);

    k_ntm<<<NTM_BLOCKS, 256, 0, stream>>>(x, W_l, b_l, W_r, b_r,
                                          ei, count,
                                          W1, b1, gamma, beta, bias_gat, W2,
                                          W1p, b1p, gammap, betap, biasgp, W2p,
                                          xl_t, xr_t);
    k_scan<<<1, 1024, 0, stream>>>(count, off);
    k_scatter<<<(N_EDGES + 255) / 256, 256, 0, stream>>>(ei, off, cursor,
                                                         edge_attr, ea_bf, eaok ? 1 : 0,
                                                         csr_src, eid_csr);
    if (f32ok && eaok) {
        k_edgeagg<true, true><<<EDGE_BLOCKS, 256, 0, stream>>>(off, csr_src, eid_csr, edge_attr,
                                                               ea_bf, W_e, att, xl_t, xr_t, zs_g);
        k_post<true><<<(N_NODES + 63) / 64, 256, 0, stream>>>(zs_g, x, biasgp,
                                                              W1p, b1p, gammap, betap, W2p, b2, out);
    } else if (f32ok) {
        k_edgeagg<true, false><<<EDGE_BLOCKS, 256, 0, stream>>>(off, csr_src, eid_csr, edge_attr,
                                                                ea_bf, W_e, att, xl_t, xr_t, zs_g);
        k_post<true><<<(N_NODES + 63) / 64, 256, 0, stream>>>(zs_g, x, biasgp,
                                                              W1p, b1p, gammap, betap, W2p, b2, out);
    } else {
        k_edgeagg<false, false><<<EDGE_BLOCKS, 256, 0, stream>>>(off, csr_src, eid_csr, edge_attr,
                                                                 ea_bf, W_e, att, xl_t, xr_t, zs_g);
        k_post<false><<<(N_NODES + 63) / 64, 256, 0, stream>>>(zs_g, x, biasgp,
                                                               W1p, b1p, gammap, betap, W2p, b2, out);
    }
}

// Round 24
// 516.607 us; speedup vs baseline: 1.0490x; 1.0136x over previous
//
#include <hip/hip_runtime.h>
#include <math.h>

#define N_NODES 50000
#define N_EDGES 800000
#define HID 64
#define HEADS 4
#define HC 256
#define NEG_SLOPE 0.2f
#define LN_EPS 1e-5f
#define EDGE_BLOCKS 2048   // persistent-wave grid for k_edgeagg (8192 waves)
#define NTM_BLOCKS 782     // ceil(50000/64); hist slice sized to cover edges

typedef __attribute__((ext_vector_type(8))) short bf16x8;
typedef __attribute__((ext_vector_type(8))) unsigned short u16x8;
typedef __attribute__((ext_vector_type(4))) float f32x4;

__device__ __forceinline__ float bf2f(unsigned short u) {
    return __uint_as_float(((unsigned int)u) << 16);
}
__device__ __forceinline__ unsigned short f2bf(float f) {
    unsigned int u = __float_as_uint(f);
    u = (u + 0x7fffu + ((u >> 16) & 1u)) >> 16;   // RNE
    return (unsigned short)u;
}
__device__ __forceinline__ float fast_tanh(float v) {
    const float c = fminf(fmaxf(v, -15.f), 15.f);
    const float e = __expf(2.f * c);
    return 1.f - 2.f / (e + 1.f);
}
__device__ __forceinline__ bf16x8 pack_bf8(float4 a, float4 b) {
    u16x8 r;
    r[0] = f2bf(a.x); r[1] = f2bf(a.y); r[2] = f2bf(a.z); r[3] = f2bf(a.w);
    r[4] = f2bf(b.x); r[5] = f2bf(b.y); r[6] = f2bf(b.z); r[7] = f2bf(b.w);
    return __builtin_bit_cast(bf16x8, r);
}

// ---------------- K1: MFMA node transform + fused hist + permw -------------
__global__ __launch_bounds__(256) void k_ntm(
    const float* __restrict__ x,
    const float* __restrict__ W_l, const float* __restrict__ b_l,
    const float* __restrict__ W_r, const float* __restrict__ b_r,
    const int* __restrict__ ei, int* __restrict__ count,
    const float* __restrict__ W1, const float* __restrict__ b1,
    const float* __restrict__ gamma, const float* __restrict__ beta,
    const float* __restrict__ bias_gat, const float* __restrict__ W2,
    float* __restrict__ W1p, float* __restrict__ b1p,
    float* __restrict__ gammap, float* __restrict__ betap,
    float* __restrict__ biasgp, float* __restrict__ W2p,
    unsigned short* __restrict__ xl_t, unsigned short* __restrict__ xr_t)
{
    __shared__ unsigned short wl_s[2][16][64][8];   // 32 KB
    __shared__ unsigned short wr_s[2][16][64][8];   // 32 KB
    const int t = threadIdx.x, lane = t & 63, wv = t >> 6;
    const int arow = lane & 15, koct = lane >> 4;
    const int bid = blockIdx.x;

    // ---- hist slice (fire-and-forget atomics; 1024 edges/block covers all) --
    {
        const int e0 = bid * 1024;
#pragma unroll
        for (int j = 0; j < 4; j++) {
            const int e = e0 + j * 256 + t;
            if (e < N_EDGES) atomicAdd(&count[ei[N_EDGES + e]], 1);
        }
    }
    // ---- permw slice (last block only) ----
    if (bid == NTM_BLOCKS - 1) {
        const int c = t;
        const int pos = (c & 15) * 16 + (c >> 4);
        for (int k = 0; k < 64; k++) W1p[k * 256 + pos] = W1[k * 256 + c];
        b1p[pos] = b1[c];
        gammap[pos] = gamma[c];
        betap[pos] = beta[c];
        biasgp[pos] = bias_gat[c];
        for (int j = 0; j < 64; j++) W2p[pos * 64 + j] = W2[c * 64 + j];
    }

    // ---- W staging ----
    for (int i = t; i < 2048; i += 256) {
        const int ks = i >> 10, nt = (i >> 6) & 15, ls = i & 63;
        const int col = nt * 16 + (ls & 15);
        const int kb = ks * 32 + (ls >> 4) * 8;
        unsigned short a[8], b[8];
#pragma unroll
        for (int j = 0; j < 8; j++) {
            a[j] = f2bf(W_l[(kb + j) * 256 + col]);
            b[j] = f2bf(W_r[(kb + j) * 256 + col]);
        }
        *(ushort4*)&wl_s[ks][nt][ls][0] = make_ushort4(a[0], a[1], a[2], a[3]);
        *(ushort4*)&wl_s[ks][nt][ls][4] = make_ushort4(a[4], a[5], a[6], a[7]);
        *(ushort4*)&wr_s[ks][nt][ls][0] = make_ushort4(b[0], b[1], b[2], b[3]);
        *(ushort4*)&wr_s[ks][nt][ls][4] = make_ushort4(b[4], b[5], b[6], b[7]);
    }
    __syncthreads();

    const int n0w = bid * 64 + wv * 16;
    if (n0w >= N_NODES) return;

    const float* xrow = x + (size_t)(n0w + arow) * 64;
    const bf16x8 af0 = pack_bf8(*(const float4*)(xrow + koct * 8),
                                *(const float4*)(xrow + koct * 8 + 4));
    const bf16x8 af1 = pack_bf8(*(const float4*)(xrow + 32 + koct * 8),
                                *(const float4*)(xrow + 32 + koct * 8 + 4));

    float acc[4][16];
#pragma unroll
    for (int nt = 0; nt < 16; nt++) {
        const float bv = b_l[nt * 16 + arow];
        f32x4 d = {bv, bv, bv, bv};
        d = __builtin_amdgcn_mfma_f32_16x16x32_bf16(af0, *(const bf16x8*)&wl_s[0][nt][lane][0], d, 0, 0, 0);
        d = __builtin_amdgcn_mfma_f32_16x16x32_bf16(af1, *(const bf16x8*)&wl_s[1][nt][lane][0], d, 0, 0, 0);
#pragma unroll
        for (int r = 0; r < 4; r++) acc[r][nt] = d[r];
    }
#pragma unroll
    for (int r = 0; r < 4; r++) {
        u16x8 lo, hi;
#pragma unroll
        for (int j = 0; j < 8; j++) { lo[j] = f2bf(acc[r][j]); hi[j] = f2bf(acc[r][j + 8]); }
        unsigned short* dst = xl_t + (size_t)(n0w + koct * 4 + r) * 256 + arow * 16;
        *(u16x8*)dst = lo;
        *(u16x8*)(dst + 8) = hi;
    }
#pragma unroll
    for (int nt = 0; nt < 16; nt++) {
        const float bv = b_r[nt * 16 + arow];
        f32x4 d = {bv, bv, bv, bv};
        d = __builtin_amdgcn_mfma_f32_16x16x32_bf16(af0, *(const bf16x8*)&wr_s[0][nt][lane][0], d, 0, 0, 0);
        d = __builtin_amdgcn_mfma_f32_16x16x32_bf16(af1, *(const bf16x8*)&wr_s[1][nt][lane][0], d, 0, 0, 0);
#pragma unroll
        for (int r = 0; r < 4; r++) acc[r][nt] = d[r];
    }
#pragma unroll
    for (int r = 0; r < 4; r++) {
        u16x8 lo, hi;
#pragma unroll
        for (int j = 0; j < 8; j++) { lo[j] = f2bf(acc[r][j]); hi[j] = f2bf(acc[r][j + 8]); }
        unsigned short* dst = xr_t + (size_t)(n0w + koct * 4 + r) * 256 + arow * 16;
        *(u16x8*)dst = lo;
        *(u16x8*)(dst + 8) = hi;
    }
}

// ---------------- K3: exclusive scan (single block) ------------------------
__global__ __launch_bounds__(1024) void k_scan(const int* __restrict__ count, int* __restrict__ off)
{
    __shared__ int wsum[16];
    __shared__ int s_carry;
    const int t = threadIdx.x, lane = t & 63, wv = t >> 6;
    if (t == 0) s_carry = 0;
    __syncthreads();
    for (int base = 0; base < N_NODES; base += 8192) {
        const int idx0 = base + t * 8;
        int v[8];
#pragma unroll
        for (int j = 0; j < 8; j++) { int i = idx0 + j; v[j] = (i < N_NODES) ? count[i] : 0; }
#pragma unroll
        for (int j = 1; j < 8; j++) v[j] += v[j - 1];
        const int tot = v[7];
        int sc = tot;
#pragma unroll
        for (int s = 1; s < 64; s <<= 1) { int o = __shfl_up(sc, s, 64); if (lane >= s) sc += o; }
        if (lane == 63) wsum[wv] = sc;
        __syncthreads();
        const int carry = s_carry;
        int woff = 0;
        for (int u = 0; u < wv; u++) woff += wsum[u];
        const int ebase = carry + woff + (sc - tot);
#pragma unroll
        for (int j = 0; j < 8; j++) {
            int i = idx0 + j;
            if (i < N_NODES) off[i] = ebase + (j ? v[j - 1] : 0);
        }
        __syncthreads();
        if (t == 0) { int tt = 0; for (int u = 0; u < 16; u++) tt += wsum[u]; s_carry = carry + tt; }
        __syncthreads();
    }
    if (threadIdx.x == 0) off[N_NODES] = s_carry;
}

// ---------------- K4: scatter src/eid + ea->bf16 convert -------------------
__global__ __launch_bounds__(256) void k_scatter(
    const int* __restrict__ ei, const int* __restrict__ off, int* __restrict__ cursor,
    const float* __restrict__ edge_attr, unsigned short* __restrict__ ea_bf,
    const int do_ea,
    int* __restrict__ csr_src, int* __restrict__ eid_csr)
{
    const int e = blockIdx.x * 256 + threadIdx.x;
    if (e < N_EDGES) {
        const int s = ei[e];
        const int d = ei[N_EDGES + e];
        const int pos = off[d] + atomicAdd(&cursor[d], 1);
        csr_src[pos] = s;
        eid_csr[pos] = e;
        if (do_ea) {
            const float4* src4 = (const float4*)(edge_attr + (size_t)e * 32);
            ushort4* dst4 = (ushort4*)(ea_bf + (size_t)e * 32);
#pragma unroll
            for (int i = 0; i < 8; i += 2) {
                const float4 v0 = src4[i], v1 = src4[i + 1];
                dst4[i]     = make_ushort4(f2bf(v0.x), f2bf(v0.y), f2bf(v0.z), f2bf(v0.w));
                dst4[i + 1] = make_ushort4(f2bf(v1.x), f2bf(v1.y), f2bf(v1.z), f2bf(v1.w));
            }
        }
    }
}

// ---------------- K5: edge+aggregate, persistent waves, deep pipeline ------
// TILE-TOP PREFETCH: since sv/ev vectors live in registers, the upcoming
// tile's xl gathers issue at tile top (full-tile latency cover, ~2x the
// mid-tile placement).
template<bool F32, bool EABF>
__global__ __launch_bounds__(256) void k_edgeagg(
    const int* __restrict__ off, const int* __restrict__ csr_src,
    const int* __restrict__ eid_csr, const float* __restrict__ edge_attr,
    const unsigned short* __restrict__ ea_bf,
    const float* __restrict__ W_e, const float* __restrict__ att,
    const unsigned short* __restrict__ xl_t, const unsigned short* __restrict__ xr_t,
    void* __restrict__ zs_g)
{
    __shared__ unsigned short bfrag_s[16][64][8];   // 16 KB, only LDS

    const int t = threadIdx.x;
    const int lane = t & 63, wv = t >> 6;
    const int arow = lane & 15, koct = lane >> 4;

    for (int i = t; i < 1024; i += 256) {
        const int nt = i >> 6, ls = i & 63;
        const int col = nt * 16 + (ls & 15);
        const int kb = (ls >> 4) * 8;
        unsigned short tmp[8];
#pragma unroll
        for (int j = 0; j < 8; j++) tmp[j] = f2bf(W_e[(kb + j) * 256 + col]);
        *(ushort4*)&bfrag_s[nt][ls][0] = make_ushort4(tmp[0], tmp[1], tmp[2], tmp[3]);
        *(ushort4*)&bfrag_s[nt][ls][4] = make_ushort4(tmp[4], tmp[5], tmp[6], tmp[7]);
    }
    __syncthreads();

    float attLf[8], attHf[8];
#pragma unroll
    for (int j = 0; j < 8; j++) {
        attLf[j] = att[j * 16 + arow];
        attHf[j] = att[(j + 8) * 16 + arow];
    }

    const int STRIDE = EDGE_BLOCKS * 4;
    int node = blockIdx.x * 4 + wv;
    if (node >= N_NODES) return;

    int lo = off[node], hi = off[node + 1];
    u16x8 xrl = *(const u16x8*)(xr_t + (size_t)node * 256 + arow * 16);
    u16x8 xrh = *(const u16x8*)(xr_t + (size_t)node * 256 + arow * 16 + 8);
    while (hi <= lo) {
        if (F32) *(float4*)((float*)zs_g + (size_t)node * 256 + arow * 16 + koct * 4) = make_float4(0.f, 0.f, 0.f, 0.f);
        else *(ushort4*)((unsigned short*)zs_g + (size_t)node * 256 + arow * 16 + koct * 4) = make_ushort4(0, 0, 0, 0);
        node += STRIDE;
        if (node >= N_NODES) return;
        lo = off[node]; hi = off[node + 1];
        xrl = *(const u16x8*)(xr_t + (size_t)node * 256 + arow * 16);
        xrh = *(const u16x8*)(xr_t + (size_t)node * 256 + arow * 16 + 8);
    }
    int svbase = lo;
    int svall = csr_src[min(svbase + lane, hi - 1)];
    int evall = eid_csr[min(svbase + lane, hi - 1)];

    int nnode = node + STRIDE;
    bool nvalid = nnode < N_NODES;
    int nlo = 0, nhi = 0, nsvall = 0, nevall = 0;
    u16x8 nxrl = xrl, nxrh = xrh;
    if (nvalid) {
        nlo = off[nnode]; nhi = off[nnode + 1];
        nxrl = *(const u16x8*)(xr_t + (size_t)nnode * 256 + arow * 16);
        nxrh = *(const u16x8*)(xr_t + (size_t)nnode * 256 + arow * 16 + 8);
        if (nhi > nlo) {
            nsvall = csr_src[min(nlo + lane, nhi - 1)];
            nevall = eid_csr[min(nlo + lane, nhi - 1)];
        }
    }
    int p0 = lo;
    bf16x8 af;
    u16x8 xlo[4], xhi[4];
    {
        const int eid0 = __shfl(evall, arow, 64);
        if (EABF) {
            af = *(const bf16x8*)(ea_bf + (size_t)eid0 * 32 + koct * 8);
        } else {
            const float* ap = edge_attr + (size_t)eid0 * 32 + koct * 8;
            af = pack_bf8(*(const float4*)ap, *(const float4*)(ap + 4));
        }
#pragma unroll
        for (int r = 0; r < 4; r++) {
            const int sr = __shfl(svall, koct * 4 + r, 64);
            const unsigned short* bp = xl_t + (size_t)sr * 256 + arow * 16;
            xlo[r] = *(const u16x8*)bp;
            xhi[r] = *(const u16x8*)(bp + 8);
        }
    }

    float g[16];
#pragma unroll
    for (int i = 0; i < 16; i++) g[i] = 0.f;
    float dsum[4] = {0.f, 0.f, 0.f, 0.f};

    for (;;) {
        const bool last = (p0 + 16 >= hi);
        bool uvalid;
        int up0;
        if (!last) { uvalid = true; up0 = p0 + 16; }
        else {
            while (nvalid && nlo >= nhi) {
                if (F32) *(float4*)((float*)zs_g + (size_t)nnode * 256 + arow * 16 + koct * 4) = make_float4(0.f, 0.f, 0.f, 0.f);
                else *(ushort4*)((unsigned short*)zs_g + (size_t)nnode * 256 + arow * 16 + koct * 4) = make_ushort4(0, 0, 0, 0);
                nnode += STRIDE;
                nvalid = nnode < N_NODES;
                if (nvalid) {
                    nlo = off[nnode]; nhi = off[nnode + 1];
                    nxrl = *(const u16x8*)(xr_t + (size_t)nnode * 256 + arow * 16);
                    nxrh = *(const u16x8*)(xr_t + (size_t)nnode * 256 + arow * 16 + 8);
                    if (nhi > nlo) {
                        nsvall = csr_src[min(nlo + lane, nhi - 1)];
                        nevall = eid_csr[min(nlo + lane, nhi - 1)];
                    }
                }
            }
            uvalid = nvalid; up0 = nlo;
        }
        // ---- tile-top prefetch: af AND xl gathers for the upcoming tile ----
        u16x8 uAb = {0, 0, 0, 0, 0, 0, 0, 0};
        float4 uA0 = make_float4(0.f, 0.f, 0.f, 0.f), uA1 = uA0;
        u16x8 uxlo[4], uxhi[4];
        if (uvalid) {
            const int ubase = last ? 0 : (up0 - svbase);
            const int uev = last ? nevall : evall;
            const int ueid = __shfl(uev, ubase + arow, 64);
            if (EABF) {
                uAb = *(const u16x8*)(ea_bf + (size_t)ueid * 32 + koct * 8);
            } else {
                const float* ap = edge_attr + (size_t)ueid * 32 + koct * 8;
                uA0 = *(const float4*)ap;
                uA1 = *(const float4*)(ap + 4);
            }
            const int usrcv = last ? nsvall : svall;
#pragma unroll
            for (int r = 0; r < 4; r++) {
                const int sr = __shfl(usrcv, ubase + koct * 4 + r, 64);
                const unsigned short* bp = xl_t + (size_t)sr * 256 + arow * 16;
                uxlo[r] = *(const u16x8*)bp;
                uxhi[r] = *(const u16x8*)(bp + 8);
            }
        } else {
#pragma unroll
            for (int r = 0; r < 4; r++) { uxlo[r] = xlo[r]; uxhi[r] = xhi[r]; }
        }

        float s_[4][4];
#pragma unroll
        for (int r = 0; r < 4; r++)
#pragma unroll
            for (int h = 0; h < 4; h++) s_[r][h] = 0.f;

#pragma unroll
        for (int nt = 0; nt < 8; nt++) {
            const bf16x8 bfr = *(const bf16x8*)&bfrag_s[nt][lane][0];
            const float xrv = bf2f((unsigned short)xrl[nt]);
            f32x4 dacc = {xrv, xrv, xrv, xrv};
            dacc = __builtin_amdgcn_mfma_f32_16x16x32_bf16(af, bfr, dacc, 0, 0, 0);
            const float atv = attLf[nt];
            const int h = nt >> 2;
#pragma unroll
            for (int r = 0; r < 4; r++) {
                const float mm = dacc[r] + bf2f((unsigned short)xlo[r][nt]);
                const float lk = fmaxf(mm, NEG_SLOPE * mm);
                s_[r][h] = fmaf(atv, lk, s_[r][h]);
            }
        }
#pragma unroll
        for (int n2 = 0; n2 < 8; n2++) {
            const int nt = n2 + 8;
            const bf16x8 bfr = *(const bf16x8*)&bfrag_s[nt][lane][0];
            const float xrv = bf2f((unsigned short)xrh[n2]);
            f32x4 dacc = {xrv, xrv, xrv, xrv};
            dacc = __builtin_amdgcn_mfma_f32_16x16x32_bf16(af, bfr, dacc, 0, 0, 0);
            const float atv = attHf[n2];
            const int h = nt >> 2;
#pragma unroll
            for (int r = 0; r < 4; r++) {
                const float mm = dacc[r] + bf2f((unsigned short)xhi[r][n2]);
                const float lk = fmaxf(mm, NEG_SLOPE * mm);
                s_[r][h] = fmaf(atv, lk, s_[r][h]);
            }
        }
#pragma unroll
        for (int r = 0; r < 4; r++)
#pragma unroll
            for (int h = 0; h < 4; h++) {
                float v = s_[r][h];
                v += __shfl_xor(v, 1, 64);
                v += __shfl_xor(v, 2, 64);
                v += __shfl_xor(v, 4, 64);
                v += __shfl_xor(v, 8, 64);
                s_[r][h] = v;
            }
#pragma unroll
        for (int h = 0; h < 4; h++) {
            float w4[4];
#pragma unroll
            for (int r = 0; r < 4; r++) {
                const bool ok = (p0 + koct * 4 + r) < hi;
                w4[r] = ok ? __expf(fminf(s_[r][h], 60.f)) : 0.f;
            }
            dsum[h] += (w4[0] + w4[1]) + (w4[2] + w4[3]);
#pragma unroll
            for (int q = 0; q < 4; q++) {
                const int nt = h * 4 + q;
                float acc = g[nt];
#pragma unroll
                for (int r = 0; r < 4; r++) {
                    const float xv = bf2f((unsigned short)(nt < 8 ? xlo[r][nt & 7] : xhi[r][nt & 7]));
                    acc = fmaf(w4[r], xv, acc);
                }
                g[nt] = acc;
            }
        }

        if (last) {
#pragma unroll
            for (int i = 0; i < 16; i++) {
                float v = g[i];
                v += __shfl_xor(v, 16, 64);
                v += __shfl_xor(v, 32, 64);
                g[i] = v;
            }
#pragma unroll
            for (int h = 0; h < 4; h++) {
                float v = dsum[h];
                v += __shfl_xor(v, 16, 64);
                v += __shfl_xor(v, 32, 64);
                dsum[h] = v;
            }
            const float inv = 1.f / (dsum[koct] + 1e-16f);
            if (F32) {
                *(float4*)((float*)zs_g + (size_t)node * 256 + arow * 16 + koct * 4) =
                    make_float4(g[koct * 4] * inv, g[koct * 4 + 1] * inv,
                                g[koct * 4 + 2] * inv, g[koct * 4 + 3] * inv);
            } else {
                *(ushort4*)((unsigned short*)zs_g + (size_t)node * 256 + arow * 16 + koct * 4) =
                    make_ushort4(f2bf(g[koct * 4] * inv), f2bf(g[koct * 4 + 1] * inv),
                                 f2bf(g[koct * 4 + 2] * inv), f2bf(g[koct * 4 + 3] * inv));
            }
            if (!uvalid) return;
            node = nnode; lo = nlo; hi = nhi; xrl = nxrl; xrh = nxrh;
            svbase = nlo; svall = nsvall; evall = nevall;
#pragma unroll
            for (int i = 0; i < 16; i++) g[i] = 0.f;
#pragma unroll
            for (int h = 0; h < 4; h++) dsum[h] = 0.f;
            nnode += STRIDE;
            nvalid = nnode < N_NODES;
            if (nvalid) {
                nlo = off[nnode]; nhi = off[nnode + 1];
                nxrl = *(const u16x8*)(xr_t + (size_t)nnode * 256 + arow * 16);
                nxrh = *(const u16x8*)(xr_t + (size_t)nnode * 256 + arow * 16 + 8);
                if (nhi > nlo) {
                    nsvall = csr_src[min(nlo + lane, nhi - 1)];
                    nevall = eid_csr[min(nlo + lane, nhi - 1)];
                }
            }
        }
        p0 = up0;
        if (EABF) af = __builtin_bit_cast(bf16x8, uAb);
        else af = pack_bf8(uA0, uA1);
#pragma unroll
        for (int r = 0; r < 4; r++) { xlo[r] = uxlo[r]; xhi[r] = uxhi[r]; }
        if (p0 - svbase >= 32) {
            svbase = p0;
            svall = csr_src[min(svbase + lane, hi - 1)];
            evall = eid_csr[min(svbase + lane, hi - 1)];
        }
    }
}

// ---------------- K6: MFMA epilogue (64 nodes/block, 4 waves x 16 nodes) ---
template<bool F32>
__global__ __launch_bounds__(256) void k_post(
    const void* __restrict__ zs_g, const float* __restrict__ x,
    const float* __restrict__ biasgp,
    const float* __restrict__ W1p, const float* __restrict__ b1p,
    const float* __restrict__ gammap, const float* __restrict__ betap,
    const float* __restrict__ W2p, const float* __restrict__ b2,
    float* __restrict__ out)
{
    __shared__ unsigned short wf[16384];        // 32 KB: w1f / w2f
    __shared__ unsigned short zsh[64][272];     // 34 KB
    __shared__ float outsh[64][64];             // 16 KB

    const int t = threadIdx.x, lane = t & 63, wv = t >> 6;
    const int arow = lane & 15, koct = lane >> 4;
    const int n0 = blockIdx.x * 64;
    const int nw = n0 + wv * 16;

    for (int i = t; i < 2048; i += 256) {
        const int ks = i >> 10, nt = (i >> 6) & 15, ls = i & 63;
        const int col = (ls & 15) * 16 + nt;
        const int kb = ks * 32 + (ls >> 4) * 8;
        unsigned short a[8];
#pragma unroll
        for (int j = 0; j < 8; j++) a[j] = f2bf(W1p[(kb + j) * 256 + col]);
        *(ushort4*)&wf[i * 8]     = make_ushort4(a[0], a[1], a[2], a[3]);
        *(ushort4*)&wf[i * 8 + 4] = make_ushort4(a[4], a[5], a[6], a[7]);
    }
    __syncthreads();

    const int xn = min(nw + arow, N_NODES - 1);
    const float* xrow = x + (size_t)xn * 64;
    const bf16x8 af0 = pack_bf8(*(const float4*)(xrow + koct * 8),
                                *(const float4*)(xrow + koct * 8 + 4));
    const bf16x8 af1 = pack_bf8(*(const float4*)(xrow + 32 + koct * 8),
                                *(const float4*)(xrow + 32 + koct * 8 + 4));

    float z[4][16];   // z[r][nt] = pos (arow*16 + nt) of node nw + koct*4 + r
#pragma unroll
    for (int nt = 0; nt < 16; nt++) {
        const float bv = b1p[arow * 16 + nt];
        f32x4 d = {bv, bv, bv, bv};
        d = __builtin_amdgcn_mfma_f32_16x16x32_bf16(af0, *(const bf16x8*)&wf[(0 * 16 + nt) * 512 + lane * 8], d, 0, 0, 0);
        d = __builtin_amdgcn_mfma_f32_16x16x32_bf16(af1, *(const bf16x8*)&wf[(1 * 16 + nt) * 512 + lane * 8], d, 0, 0, 0);
#pragma unroll
        for (int r = 0; r < 4; r++) z[r][nt] = d[r];
    }
#pragma unroll
    for (int r = 0; r < 4; r++) {
        const int nd = min(nw + koct * 4 + r, N_NODES - 1);
        float gv[16];
        if (F32) {
            const float* gp = (const float*)zs_g + (size_t)nd * 256 + arow * 16;
#pragma unroll
            for (int i4 = 0; i4 < 4; i4++) {
                const float4 v = *(const float4*)(gp + i4 * 4);
                gv[i4 * 4] = v.x; gv[i4 * 4 + 1] = v.y; gv[i4 * 4 + 2] = v.z; gv[i4 * 4 + 3] = v.w;
            }
        } else {
            const unsigned short* gp = (const unsigned short*)zs_g + (size_t)nd * 256 + arow * 16;
            const u16x8 a = *(const u16x8*)gp;
            const u16x8 b = *(const u16x8*)(gp + 8);
#pragma unroll
            for (int j = 0; j < 8; j++) { gv[j] = bf2f((unsigned short)a[j]); gv[j + 8] = bf2f((unsigned short)b[j]); }
        }
#pragma unroll
        for (int nt = 0; nt < 16; nt++)
            z[r][nt] = fast_tanh(z[r][nt]) + gv[nt] + biasgp[arow * 16 + nt];
    }
#pragma unroll
    for (int r = 0; r < 4; r++) {
        float s = 0.f, q = 0.f;
#pragma unroll
        for (int nt = 0; nt < 16; nt++) { s += z[r][nt]; q = fmaf(z[r][nt], z[r][nt], q); }
        s += __shfl_xor(s, 1, 64); q += __shfl_xor(q, 1, 64);
        s += __shfl_xor(s, 2, 64); q += __shfl_xor(q, 2, 64);
        s += __shfl_xor(s, 4, 64); q += __shfl_xor(q, 4, 64);
        s += __shfl_xor(s, 8, 64); q += __shfl_xor(q, 8, 64);
        const float mu = s * (1.f / 256.f);
        const float var = q * (1.f / 256.f) - mu * mu;
        const float ivn = rsqrtf(var + LN_EPS);
        u16x8 lo, hi;
#pragma unroll
        for (int nt = 0; nt < 16; nt++) {
            const float zn = (z[r][nt] - mu) * ivn * gammap[arow * 16 + nt] + betap[arow * 16 + nt];
            if (nt < 8) lo[nt] = f2bf(zn); else hi[nt - 8] = f2bf(zn);
        }
        unsigned short* dst = &zsh[wv * 16 + koct * 4 + r][arow * 16];
        *(u16x8*)dst = lo;
        *(u16x8*)(dst + 8) = hi;
    }
    __syncthreads();
    for (int i = t; i < 2048; i += 256) {
        const int kb = i >> 8, ct = (i >> 6) & 3, ls = i & 63;
        const int col = ct * 16 + (ls & 15);
        const int k0 = kb * 32 + (ls >> 4) * 8;
        unsigned short a[8];
#pragma unroll
        for (int j = 0; j < 8; j++) a[j] = f2bf(W2p[(k0 + j) * 64 + col]);
        *(ushort4*)&wf[i * 8]     = make_ushort4(a[0], a[1], a[2], a[3]);
        *(ushort4*)&wf[i * 8 + 4] = make_ushort4(a[4], a[5], a[6], a[7]);
    }
    __syncthreads();
    f32x4 acc2[4];
#pragma unroll
    for (int ct = 0; ct < 4; ct++) {
        const float bv = b2[ct * 16 + arow];
        acc2[ct][0] = bv; acc2[ct][1] = bv; acc2[ct][2] = bv; acc2[ct][3] = bv;
    }
#pragma unroll
    for (int kb = 0; kb < 8; kb++) {
        const bf16x8 a = *(const bf16x8*)&zsh[wv * 16 + arow][kb * 32 + koct * 8];
#pragma unroll
        for (int ct = 0; ct < 4; ct++)
            acc2[ct] = __builtin_amdgcn_mfma_f32_16x16x32_bf16(
                a, *(const bf16x8*)&wf[((kb * 4 + ct) * 64 + lane) * 8], acc2[ct], 0, 0, 0);
    }
#pragma unroll
    for (int ct = 0; ct < 4; ct++)
#pragma unroll
        for (int r = 0; r < 4; r++)
            outsh[wv * 16 + koct * 4 + r][ct * 16 + arow] = fast_tanh(acc2[ct][r]);
    __syncthreads();
    for (int i = t; i < 4096; i += 256) {
        const int row = i >> 6;
        if (n0 + row < N_NODES)
            out[(size_t)(n0 + row) * 64 + (i & 63)] = outsh[row][i & 63];
    }
}

// ---------------- launcher --------------------------------------------------
extern "C" void kernel_launch(void* const* d_in, const int* in_sizes, int n_in,
                              void* d_out, int out_size, void* d_ws, size_t ws_size,
                              hipStream_t stream)
{
    const float* x         = (const float*)d_in[0];
    const int*   ei        = (const int*)d_in[1];
    const float* edge_attr = (const float*)d_in[2];
    const float* W_l       = (const float*)d_in[3];
    const float* b_l       = (const float*)d_in[4];
    const float* W_r       = (const float*)d_in[5];
    const float* b_r       = (const float*)d_in[6];
    const float* W_e       = (const float*)d_in[7];
    const float* att       = (const float*)d_in[8];
    const float* bias_gat  = (const float*)d_in[9];
    const float* W1        = (const float*)d_in[10];
    const float* b1        = (const float*)d_in[11];
    const float* gamma     = (const float*)d_in[12];
    const float* beta      = (const float*)d_in[13];
    const float* W2        = (const float*)d_in[14];
    const float* b2        = (const float*)d_in[15];
    float* out = (float*)d_out;

    char* wsb = (char*)d_ws;
    size_t o = 0;
    unsigned short* xl_t   = (unsigned short*)(wsb + o);  o += (size_t)N_NODES * HC * 2;
    unsigned short* xr_t   = (unsigned short*)(wsb + o);  o += (size_t)N_NODES * HC * 2;
    int* csr_src           = (int*)(wsb + o);             o += (size_t)N_EDGES * 4;
    int* eid_csr           = (int*)(wsb + o);             o += (size_t)N_EDGES * 4;
    int* count             = (int*)(wsb + o);             o += (size_t)N_NODES * 4;
    int* cursor            = (int*)(wsb + o);             o += (size_t)N_NODES * 4;
    int* off               = (int*)(wsb + o);             o += (size_t)(N_NODES + 1) * 4;
    float* W1p             = (float*)(wsb + o);           o += 64 * 256 * 4;
    float* W2p             = (float*)(wsb + o);           o += 256 * 64 * 4;
    float* b1p             = (float*)(wsb + o);           o += 256 * 4;
    float* gammap          = (float*)(wsb + o);           o += 256 * 4;
    float* betap           = (float*)(wsb + o);           o += 256 * 4;
    float* biasgp          = (float*)(wsb + o);           o += 256 * 4;
    o = (o + 255) & ~(size_t)255;
    void* zs_g             = (void*)(wsb + o);
    const size_t zs_f32_bytes = (size_t)N_NODES * HC * 4;
    const size_t ea_bytes     = (size_t)N_EDGES * 32 * 2;
    const bool f32ok = (o + zs_f32_bytes) <= ws_size;
    size_t o_ea = o + (f32ok ? zs_f32_bytes : (size_t)N_NODES * HC * 2);
    o_ea = (o_ea + 255) & ~(size_t)255;
    const bool eaok = (o_ea + ea_bytes) <= ws_size;
    unsigned short* ea_bf = (unsigned short*)(wsb + o_ea);

    hipMemsetAsync(count, 0, 2 * (size_t)N_NODES * sizeof(int), stream);

    k_ntm<<<NTM_BLOCKS, 256, 0, stream>>>(x, W_l, b_l, W_r, b_r,
                                          ei, count,
                                          W1, b1, gamma, beta, bias_gat, W2,
                                          W1p, b1p, gammap, betap, biasgp, W2p,
                                          xl_t, xr_t);
    k_scan<<<1, 1024, 0, stream>>>(count, off);
    k_scatter<<<(N_EDGES + 255) / 256, 256, 0, stream>>>(ei, off, cursor,
                                                         edge_attr, ea_bf, eaok ? 1 : 0,
                                                         csr_src, eid_csr);
    if (f32ok && eaok) {
        k_edgeagg<true, true><<<EDGE_BLOCKS, 256, 0, stream>>>(off, csr_src, eid_csr, edge_attr,
                                                               ea_bf, W_e, att, xl_t, xr_t, zs_g);
        k_post<true><<<(N_NODES + 63) / 64, 256, 0, stream>>>(zs_g, x, biasgp,
                                                              W1p, b1p, gammap, betap, W2p, b2, out);
    } else if (f32ok) {
        k_edgeagg<true, false><<<EDGE_BLOCKS, 256, 0, stream>>>(off, csr_src, eid_csr, edge_attr,
                                                                ea_bf, W_e, att, xl_t, xr_t, zs_g);
        k_post<true><<<(N_NODES + 63) / 64, 256, 0, stream>>>(zs_g, x, biasgp,
                                                              W1p, b1p, gammap, betap, W2p, b2, out);
    } else {
        k_edgeagg<false, false><<<EDGE_BLOCKS, 256, 0, stream>>>(off, csr_src, eid_csr, edge_attr,
                                                                 ea_bf, W_e, att, xl_t, xr_t, zs_g);
        k_post<false><<<(N_NODES + 63) / 64, 256, 0, stream>>>(zs_g, x, biasgp,
                                                               W1p, b1p, gammap, betap, W2p, b2, out);
    }
}